// Round 2
// baseline (727.974 us; speedup 1.0000x reference)
//
#include <hip/hip_runtime.h>

#define N_NODES 100000
#define N_EDGES 1600000

// ---------------- degree / CSR build ----------------
// NOTE: harness delivers integer inputs as int32 (edge_index reference was
// int64 but arrives as const int*).

__global__ __launch_bounds__(256) void count_deg_k(const int* __restrict__ ei,
                                                   int* __restrict__ deg) {
  int idx = blockIdx.x * blockDim.x + threadIdx.x;
  int stride = gridDim.x * blockDim.x;
  for (int e = idx; e < N_EDGES; e += stride) {
    atomicAdd(&deg[ei[e]], 1);
  }
}

__global__ __launch_bounds__(256) void dinv_k(const int* __restrict__ deg,
                                              float* __restrict__ dinv) {
  int i = blockIdx.x * 256 + threadIdx.x;
  if (i < N_NODES) dinv[i] = rsqrtf((float)deg[i] + 1.0f);  // +1 = self-loop
}

__global__ __launch_bounds__(1024) void scan_block_k(const int* __restrict__ deg,
                                                     int* __restrict__ incl,
                                                     int* __restrict__ bsums) {
  __shared__ int s[1024];
  int i = blockIdx.x * 1024 + threadIdx.x;
  int v = (i < N_NODES) ? deg[i] : 0;
  s[threadIdx.x] = v;
  __syncthreads();
  for (int d = 1; d < 1024; d <<= 1) {
    int t = (threadIdx.x >= d) ? s[threadIdx.x - d] : 0;
    __syncthreads();
    s[threadIdx.x] += t;
    __syncthreads();
  }
  if (i < N_NODES) incl[i] = s[threadIdx.x];
  if (threadIdx.x == 1023) bsums[blockIdx.x] = s[1023];
}

__global__ void scan_bsums_k(int* bsums, int nb) {
  if (blockIdx.x == 0 && threadIdx.x == 0) {
    int run = 0;
    for (int b = 0; b < nb; b++) { int v = bsums[b]; bsums[b] = run; run += v; }
  }
}

__global__ __launch_bounds__(256) void finalize_off_k(const int* __restrict__ incl,
                                                      const int* __restrict__ bsums,
                                                      const int* __restrict__ deg,
                                                      int* __restrict__ off,
                                                      int* __restrict__ cursor) {
  int i = blockIdx.x * 256 + threadIdx.x;
  if (i < N_NODES) {
    int inext = incl[i] + bsums[i >> 10];  // inclusive scan = off[i+1]
    off[i + 1] = inext;
    cursor[i] = inext - deg[i];            // off[i]
  }
  if (i == 0) off[0] = 0;
}

__global__ __launch_bounds__(256) void scatter_k(const int* __restrict__ ei,
                                                 int* __restrict__ cursor,
                                                 int* __restrict__ scol) {
  int idx = blockIdx.x * blockDim.x + threadIdx.x;
  int stride = gridDim.x * blockDim.x;
  for (int e = idx; e < N_EDGES; e += stride) {
    int r = ei[e];
    int c = ei[N_EDGES + e];
    int slot = atomicAdd(&cursor[r], 1);
    scol[slot] = c;
  }
}

// ---------------- GCN propagate: per-node gather, one wave per node ----------------

__global__ __launch_bounds__(256) void prop_k(const float* __restrict__ X,
                                              float* __restrict__ Y,
                                              const int* __restrict__ off,
                                              const int* __restrict__ scol,
                                              const float* __restrict__ dinv) {
  int node = blockIdx.x * 4 + (threadIdx.x >> 6);
  if (node >= N_NODES) return;
  int lane = threadIdx.x & 63;
  float di = dinv[node];
  const float2* Xv = (const float2*)X;
  float2 self = Xv[(size_t)node * 64 + lane];
  float sc = di * di;
  float2 acc;
  acc.x = self.x * sc;
  acc.y = self.y * sc;
  int e = off[node], e1 = off[node + 1];
  for (; e + 1 < e1; e += 2) {
    int c0 = scol[e], c1 = scol[e + 1];
    float k0 = di * dinv[c0], k1 = di * dinv[c1];
    float2 v0 = Xv[(size_t)c0 * 64 + lane];
    float2 v1 = Xv[(size_t)c1 * 64 + lane];
    acc.x += v0.x * k0 + v1.x * k1;
    acc.y += v0.y * k0 + v1.y * k1;
  }
  if (e < e1) {
    int c0 = scol[e];
    float k0 = di * dinv[c0];
    float2 v0 = Xv[(size_t)c0 * 64 + lane];
    acc.x += v0.x * k0;
    acc.y += v0.y * k0;
  }
  ((float2*)Y)[(size_t)node * 64 + lane] = acc;
}

// ---------------- fp32 GEMM, K=128, register-tiled ----------------
// C[n,FOUT] = A[n,128] @ W[128,FOUT]; block tile 64 rows x FOUT cols.

template <int FOUT, bool RELU>
__global__ __launch_bounds__(256) void gemm_k128(const float* __restrict__ A,
                                                 const float* __restrict__ W,
                                                 float* __restrict__ C) {
  __shared__ float Wl[128 * FOUT];
  __shared__ float Al[64 * 128];
  constexpr int TC = FOUT / 4;        // thread-cols (32 or 16)
  constexpr int R = 64 / (256 / TC);  // rows per thread (8 or 4)
  int tid = threadIdx.x;
  for (int i = tid; i < 128 * FOUT / 4; i += 256)
    ((float4*)Wl)[i] = ((const float4*)W)[i];
  int row0 = blockIdx.x * 64;
  for (int i = tid; i < 64 * 128 / 4; i += 256) {
    int r = i >> 5;  // 32 float4 per row
    int gr = row0 + r;
    float4 v = make_float4(0.f, 0.f, 0.f, 0.f);
    if (gr < N_NODES) v = ((const float4*)A)[(size_t)gr * 32 + (i & 31)];
    ((float4*)Al)[i] = v;
  }
  __syncthreads();
  int tc = tid % TC, tr = tid / TC;
  int c0 = tc * 4, r0 = tr * R;
  float acc[R][4];
#pragma unroll
  for (int r = 0; r < R; r++)
#pragma unroll
    for (int c = 0; c < 4; c++) acc[r][c] = 0.f;

  for (int k = 0; k < 128; k += 4) {
    float4 w[4];
#pragma unroll
    for (int kk = 0; kk < 4; kk++) w[kk] = *(const float4*)&Wl[(k + kk) * FOUT + c0];
    float4 a[R];
#pragma unroll
    for (int r = 0; r < R; r++) a[r] = *(const float4*)&Al[(r0 + r) * 128 + k];
#pragma unroll
    for (int kk = 0; kk < 4; kk++) {
#pragma unroll
      for (int r = 0; r < R; r++) {
        float av = (kk == 0) ? a[r].x : (kk == 1) ? a[r].y : (kk == 2) ? a[r].z : a[r].w;
        acc[r][0] += av * w[kk].x;
        acc[r][1] += av * w[kk].y;
        acc[r][2] += av * w[kk].z;
        acc[r][3] += av * w[kk].w;
      }
    }
  }
#pragma unroll
  for (int r = 0; r < R; r++) {
    int gr = row0 + r0 + r;
    if (gr < N_NODES) {
      float4 v;
      v.x = acc[r][0]; v.y = acc[r][1]; v.z = acc[r][2]; v.w = acc[r][3];
      if (RELU) {
        v.x = fmaxf(v.x, 0.f); v.y = fmaxf(v.y, 0.f);
        v.z = fmaxf(v.z, 0.f); v.w = fmaxf(v.w, 0.f);
      }
      ((float4*)C)[(size_t)gr * (FOUT / 4) + tc] = v;
    }
  }
}

// ---------------- launch ----------------

extern "C" void kernel_launch(void* const* d_in, const int* in_sizes, int n_in,
                              void* d_out, int out_size, void* d_ws, size_t ws_size,
                              hipStream_t stream) {
  const float* feat = (const float*)d_in[0];
  const int* ei = (const int*)d_in[1];   // int32 per harness contract
  const float* W0 = (const float*)d_in[2];
  const float* W1 = (const float*)d_in[3];
  const float* W2 = (const float*)d_in[4];
  float* out = (float*)d_out;

  char* ws = (char*)d_ws;
  float* x0 = (float*)ws;   ws += (size_t)N_NODES * 128 * 4;
  float* x1 = (float*)ws;   ws += (size_t)N_NODES * 128 * 4;
  float* dinv = (float*)ws; ws += (size_t)N_NODES * 4;
  int* deg = (int*)ws;      ws += (size_t)N_NODES * 4;
  int* incl = (int*)ws;     ws += (size_t)N_NODES * 4;
  int* off = (int*)ws;      ws += (size_t)(N_NODES + 1) * 4;
  int* cursor = (int*)ws;   ws += (size_t)N_NODES * 4;
  int* bsums = (int*)ws;    ws += 128 * 4;
  int* scol = (int*)ws;     ws += (size_t)N_EDGES * 4;

  const int nb_scan = (N_NODES + 1023) / 1024;

  hipMemsetAsync(deg, 0, (size_t)N_NODES * 4, stream);
  count_deg_k<<<2048, 256, 0, stream>>>(ei, deg);
  dinv_k<<<(N_NODES + 255) / 256, 256, 0, stream>>>(deg, dinv);
  scan_block_k<<<nb_scan, 1024, 0, stream>>>(deg, incl, bsums);
  scan_bsums_k<<<1, 1, 0, stream>>>(bsums, nb_scan);
  finalize_off_k<<<(N_NODES + 255) / 256, 256, 0, stream>>>(incl, bsums, deg, off, cursor);
  scatter_k<<<2048, 256, 0, stream>>>(ei, cursor, scol);

  gemm_k128<128, false><<<(N_NODES + 63) / 64, 256, 0, stream>>>(feat, W0, x0);
  prop_k<<<(N_NODES + 3) / 4, 256, 0, stream>>>(x0, x1, off, scol, dinv);
  gemm_k128<128, true><<<(N_NODES + 63) / 64, 256, 0, stream>>>(x1, W1, x0);
  prop_k<<<(N_NODES + 3) / 4, 256, 0, stream>>>(x0, x1, off, scol, dinv);
  gemm_k128<64, false><<<(N_NODES + 63) / 64, 256, 0, stream>>>(x1, W2, out);
}

// Round 3
// 412.320 us; speedup vs baseline: 1.7656x; 1.7656x over previous
//
#include <hip/hip_runtime.h>

#define N_NODES 100000
#define N_EDGES 1600000
#define NB 391            // ceil(N_NODES/256) row-buckets of 256 rows
#define NBLK 256          // blocks for binning passes
#define CHUNK 6250        // ceil(N_EDGES/NBLK)

// ---------------- pass 1: per-block bucket histogram + global degree ----------------

__global__ __launch_bounds__(256) void hist_deg_k(const int* __restrict__ ei,
                                                  int* __restrict__ hist,
                                                  int* __restrict__ deg) {
  __shared__ int lh[NB];
  for (int i = threadIdx.x; i < NB; i += 256) lh[i] = 0;
  __syncthreads();
  int b = blockIdx.x;
  int e1 = min(b * CHUNK + CHUNK, N_EDGES);
  for (int e = b * CHUNK + threadIdx.x; e < e1; e += 256) {
    int r = ei[e];
    atomicAdd(&lh[r >> 8], 1);
    atomicAdd(&deg[r], 1);
  }
  __syncthreads();
  for (int i = threadIdx.x; i < NB; i += 256) hist[b * NB + i] = lh[i];
}

__global__ __launch_bounds__(256) void dinv_k(const int* __restrict__ deg,
                                              float* __restrict__ dinv) {
  int i = blockIdx.x * 256 + threadIdx.x;
  if (i < N_NODES) dinv[i] = rsqrtf((float)deg[i] + 1.0f);  // +1 = self-loop
}

// ---------------- off[] scan over deg ----------------

__global__ __launch_bounds__(1024) void scan_block_k(const int* __restrict__ deg,
                                                     int* __restrict__ incl,
                                                     int* __restrict__ bsums) {
  __shared__ int s[1024];
  int i = blockIdx.x * 1024 + threadIdx.x;
  int v = (i < N_NODES) ? deg[i] : 0;
  s[threadIdx.x] = v;
  __syncthreads();
  for (int d = 1; d < 1024; d <<= 1) {
    int t = (threadIdx.x >= d) ? s[threadIdx.x - d] : 0;
    __syncthreads();
    s[threadIdx.x] += t;
    __syncthreads();
  }
  if (i < N_NODES) incl[i] = s[threadIdx.x];
  if (threadIdx.x == 1023) bsums[blockIdx.x] = s[1023];
}

__global__ void scan_bsums_k(int* bsums, int nb) {
  if (threadIdx.x == 0) {
    int run = 0;
    for (int b = 0; b < nb; b++) { int v = bsums[b]; bsums[b] = run; run += v; }
  }
}

__global__ __launch_bounds__(256) void finalize_off_k(const int* __restrict__ incl,
                                                      const int* __restrict__ bsums,
                                                      int* __restrict__ off) {
  int i = blockIdx.x * 256 + threadIdx.x;
  if (i < N_NODES) off[i + 1] = incl[i] + bsums[i >> 10];
  if (i == 0) off[0] = 0;
}

// ---------------- pass 2: column-scan of histograms -> per-(block,bucket) write pos ----

__global__ __launch_bounds__(64) void scan_hist_k(const int* __restrict__ hist,
                                                  const int* __restrict__ off,
                                                  int* __restrict__ pos) {
  int k = blockIdx.x, lane = threadIdx.x;
  int carry = off[k << 8];  // bucket start in CSR space
  for (int c = 0; c < 4; c++) {
    int b = c * 64 + lane;
    int v = hist[b * NB + k];
    int x = v;
    for (int d = 1; d < 64; d <<= 1) {
      int t = __shfl_up(x, d);
      if (lane >= d) x += t;
    }
    pos[b * NB + k] = carry + x - v;  // exclusive
    carry += __shfl(x, 63);
  }
}

// ---------------- pass 3: stable binned scatter (sequential runs per block/bucket) ----

__global__ __launch_bounds__(256) void bin_k(const int* __restrict__ ei,
                                             const int* __restrict__ pos,
                                             unsigned* __restrict__ binbuf) {
  __shared__ int lcur[NB];
  int b = blockIdx.x;
  for (int i = threadIdx.x; i < NB; i += 256) lcur[i] = pos[b * NB + i];
  __syncthreads();
  int e1 = min(b * CHUNK + CHUNK, N_EDGES);
  for (int e = b * CHUNK + threadIdx.x; e < e1; e += 256) {
    int r = ei[e];
    int c = ei[N_EDGES + e];
    int p = atomicAdd(&lcur[r >> 8], 1);
    binbuf[p] = ((unsigned)(r & 255) << 24) | (unsigned)c;  // c < 2^17 fits
  }
}

// ---------------- pass 4: within-bucket placement + coef fuse ----------------

__global__ __launch_bounds__(256) void csr_k(const unsigned* __restrict__ binbuf,
                                             const int* __restrict__ off,
                                             const float* __restrict__ dinv,
                                             int2* __restrict__ cc) {
  __shared__ int cur[256];
  int b = blockIdx.x, row0 = b << 8;
  int nrows = min(256, N_NODES - row0);
  if (threadIdx.x < nrows) cur[threadIdx.x] = off[row0 + threadIdx.x];
  __syncthreads();
  int e0 = off[row0];
  int e1 = off[min(row0 + 256, N_NODES)];
  for (int e = e0 + threadIdx.x; e < e1; e += 256) {
    unsigned u = binbuf[e];
    int rl = u >> 24;
    int c = (int)(u & 0xFFFFFFu);
    int slot = atomicAdd(&cur[rl], 1);
    float w = dinv[row0 + rl] * dinv[c];
    cc[slot] = make_int2(c, __float_as_int(w));
  }
}

// ---------------- W01 = W0 @ W1 (128x128x128, tiny) ----------------

__global__ __launch_bounds__(256) void w01_k(const float* __restrict__ W0,
                                             const float* __restrict__ W1,
                                             float* __restrict__ W01) {
  int g = blockIdx.x * 256 + threadIdx.x;  // 16384 outputs
  int i = g >> 7, j = g & 127;
  float s = 0.f;
  for (int k = 0; k < 128; k++) s = fmaf(W0[i * 128 + k], W1[k * 128 + j], s);
  W01[g] = s;
}

// ---------------- GCN propagate (gather, CSR + packed coef), unroll 4 ----------------

template <bool RELU>
__global__ __launch_bounds__(256) void prop128_k(const float* __restrict__ X,
                                                 float* __restrict__ Y,
                                                 const int* __restrict__ off,
                                                 const int2* __restrict__ cc,
                                                 const float* __restrict__ dinv) {
  int node = blockIdx.x * 4 + (threadIdx.x >> 6);
  if (node >= N_NODES) return;
  int lane = threadIdx.x & 63;
  const float2* Xv = (const float2*)X;
  float di = dinv[node];
  float2 self = Xv[(size_t)node * 64 + lane];
  float2 acc = make_float2(self.x * di * di, self.y * di * di);
  int e = off[node], e1 = off[node + 1];
  for (; e + 3 < e1; e += 4) {
    int2 q0 = cc[e], q1 = cc[e + 1], q2 = cc[e + 2], q3 = cc[e + 3];
    float2 v0 = Xv[(size_t)q0.x * 64 + lane];
    float2 v1 = Xv[(size_t)q1.x * 64 + lane];
    float2 v2 = Xv[(size_t)q2.x * 64 + lane];
    float2 v3 = Xv[(size_t)q3.x * 64 + lane];
    float w0 = __int_as_float(q0.y), w1 = __int_as_float(q1.y);
    float w2 = __int_as_float(q2.y), w3 = __int_as_float(q3.y);
    acc.x = fmaf(v0.x, w0, fmaf(v1.x, w1, fmaf(v2.x, w2, fmaf(v3.x, w3, acc.x))));
    acc.y = fmaf(v0.y, w0, fmaf(v1.y, w1, fmaf(v2.y, w2, fmaf(v3.y, w3, acc.y))));
  }
  for (; e < e1; e++) {
    int2 q = cc[e];
    float2 v = Xv[(size_t)q.x * 64 + lane];
    float w = __int_as_float(q.y);
    acc.x = fmaf(v.x, w, acc.x);
    acc.y = fmaf(v.y, w, acc.y);
  }
  if (RELU) { acc.x = fmaxf(acc.x, 0.f); acc.y = fmaxf(acc.y, 0.f); }
  ((float2*)Y)[(size_t)node * 64 + lane] = acc;
}

__global__ __launch_bounds__(256) void prop64_k(const float* __restrict__ X,
                                                float* __restrict__ Y,
                                                const int* __restrict__ off,
                                                const int2* __restrict__ cc,
                                                const float* __restrict__ dinv) {
  int node = blockIdx.x * 4 + (threadIdx.x >> 6);
  if (node >= N_NODES) return;
  int lane = threadIdx.x & 63;
  float di = dinv[node];
  float acc = X[(size_t)node * 64 + lane] * di * di;
  int e = off[node], e1 = off[node + 1];
  for (; e + 3 < e1; e += 4) {
    int2 q0 = cc[e], q1 = cc[e + 1], q2 = cc[e + 2], q3 = cc[e + 3];
    float v0 = X[(size_t)q0.x * 64 + lane];
    float v1 = X[(size_t)q1.x * 64 + lane];
    float v2 = X[(size_t)q2.x * 64 + lane];
    float v3 = X[(size_t)q3.x * 64 + lane];
    acc = fmaf(v0, __int_as_float(q0.y),
          fmaf(v1, __int_as_float(q1.y),
          fmaf(v2, __int_as_float(q2.y),
          fmaf(v3, __int_as_float(q3.y), acc))));
  }
  for (; e < e1; e++) {
    int2 q = cc[e];
    acc = fmaf(X[(size_t)q.x * 64 + lane], __int_as_float(q.y), acc);
  }
  Y[(size_t)node * 64 + lane] = acc;
}

// ---------------- fp32 GEMM, K=128; A-tile in LDS (32 KB), W via L1/L2 ----------------

template <int FOUT, bool RELU>
__global__ __launch_bounds__(256) void gemm_k128(const float* __restrict__ A,
                                                 const float* __restrict__ W,
                                                 float* __restrict__ C) {
  __shared__ float Al[64 * 128];      // 32 KB -> ~5 blocks/CU
  constexpr int TC = FOUT / 4;        // 32 or 16
  constexpr int R = 64 / (256 / TC);  // 8 or 4
  int tid = threadIdx.x;
  int row0 = blockIdx.x * 64;
  for (int i = tid; i < 64 * 32; i += 256) {
    int r = i >> 5;
    int gr = row0 + r;
    float4 v = make_float4(0.f, 0.f, 0.f, 0.f);
    if (gr < N_NODES) v = ((const float4*)A)[(size_t)gr * 32 + (i & 31)];
    ((float4*)Al)[i] = v;
  }
  __syncthreads();
  int tc = tid % TC, tr = tid / TC;
  int c0 = tc * 4, r0 = tr * R;
  float acc[R][4];
#pragma unroll
  for (int r = 0; r < R; r++)
#pragma unroll
    for (int c = 0; c < 4; c++) acc[r][c] = 0.f;

  for (int k = 0; k < 128; k += 4) {
    float4 w[4];
#pragma unroll
    for (int kk = 0; kk < 4; kk++) w[kk] = *(const float4*)&W[(k + kk) * FOUT + c0];
    float4 a[R];
#pragma unroll
    for (int r = 0; r < R; r++) a[r] = *(const float4*)&Al[(r0 + r) * 128 + k];
#pragma unroll
    for (int kk = 0; kk < 4; kk++) {
#pragma unroll
      for (int r = 0; r < R; r++) {
        float av = (kk == 0) ? a[r].x : (kk == 1) ? a[r].y : (kk == 2) ? a[r].z : a[r].w;
        acc[r][0] = fmaf(av, w[kk].x, acc[r][0]);
        acc[r][1] = fmaf(av, w[kk].y, acc[r][1]);
        acc[r][2] = fmaf(av, w[kk].z, acc[r][2]);
        acc[r][3] = fmaf(av, w[kk].w, acc[r][3]);
      }
    }
  }
#pragma unroll
  for (int r = 0; r < R; r++) {
    int gr = row0 + r0 + r;
    if (gr < N_NODES) {
      float4 v;
      v.x = acc[r][0]; v.y = acc[r][1]; v.z = acc[r][2]; v.w = acc[r][3];
      if (RELU) {
        v.x = fmaxf(v.x, 0.f); v.y = fmaxf(v.y, 0.f);
        v.z = fmaxf(v.z, 0.f); v.w = fmaxf(v.w, 0.f);
      }
      ((float4*)C)[(size_t)gr * (FOUT / 4) + tc] = v;
    }
  }
}

// ---------------- launch ----------------
// Pipeline (uses (PX)W == P(XW)):
//   W01 = W0@W1
//   x0  = feat @ W01
//   x1  = relu(P x0)          == relu(P(feat W0) W1)
//   t2  = x1 @ W2             (t2 aliases x0)
//   out = P t2                == P(x1) W2

extern "C" void kernel_launch(void* const* d_in, const int* in_sizes, int n_in,
                              void* d_out, int out_size, void* d_ws, size_t ws_size,
                              hipStream_t stream) {
  const float* feat = (const float*)d_in[0];
  const int* ei = (const int*)d_in[1];  // int32 per harness contract
  const float* W0 = (const float*)d_in[2];
  const float* W1 = (const float*)d_in[3];
  const float* W2 = (const float*)d_in[4];
  float* out = (float*)d_out;

  char* ws = (char*)d_ws;
  float* x0 = (float*)ws;      ws += (size_t)N_NODES * 128 * 4;   // t2 aliases x0
  float* x1 = (float*)ws;      ws += (size_t)N_NODES * 128 * 4;   // binbuf aliases x1
  int2* cc = (int2*)ws;        ws += (size_t)N_EDGES * 8;
  float* dinv = (float*)ws;    ws += (size_t)N_NODES * 4;
  int* deg = (int*)ws;         ws += (size_t)N_NODES * 4;
  int* incl = (int*)ws;        ws += (size_t)N_NODES * 4;
  int* off = (int*)ws;         ws += (size_t)(N_NODES + 2) * 4;
  int* bsums = (int*)ws;       ws += 128 * 4;
  int* hist = (int*)ws;        ws += (size_t)NBLK * NB * 4;
  int* pos = (int*)ws;         ws += (size_t)NBLK * NB * 4;
  float* W01 = (float*)ws;     ws += 128 * 128 * 4;
  unsigned* binbuf = (unsigned*)x1;  // 6.4 MB, dead before x1 is written
  float* t2 = x0;                    // 25.6 MB, x0 dead after prop128

  const int nb_scan = (N_NODES + 1023) / 1024;  // 98

  hipMemsetAsync(deg, 0, (size_t)N_NODES * 4, stream);
  hist_deg_k<<<NBLK, 256, 0, stream>>>(ei, hist, deg);
  dinv_k<<<(N_NODES + 255) / 256, 256, 0, stream>>>(deg, dinv);
  scan_block_k<<<nb_scan, 1024, 0, stream>>>(deg, incl, bsums);
  scan_bsums_k<<<1, 1, 0, stream>>>(bsums, nb_scan);
  finalize_off_k<<<(N_NODES + 255) / 256, 256, 0, stream>>>(incl, bsums, off);
  scan_hist_k<<<NB, 64, 0, stream>>>(hist, off, pos);
  bin_k<<<NBLK, 256, 0, stream>>>(ei, pos, binbuf);
  csr_k<<<NB, 256, 0, stream>>>(binbuf, off, dinv, cc);

  w01_k<<<64, 256, 0, stream>>>(W0, W1, W01);
  gemm_k128<128, false><<<(N_NODES + 63) / 64, 256, 0, stream>>>(feat, W01, x0);
  prop128_k<true><<<(N_NODES + 3) / 4, 256, 0, stream>>>(x0, x1, off, cc, dinv);
  gemm_k128<64, false><<<(N_NODES + 63) / 64, 256, 0, stream>>>(x1, W2, t2);
  prop64_k<<<(N_NODES + 3) / 4, 256, 0, stream>>>(t2, out, off, cc, dinv);
}

// Round 4
// 360.844 us; speedup vs baseline: 2.0174x; 1.1427x over previous
//
#include <hip/hip_runtime.h>

#define N_NODES 100000
#define N_EDGES 1600000
#define NB 391            // ceil(N_NODES/256) row-buckets of 256 rows
#define NBLK 256          // blocks for binning passes
#define CHUNK 6250        // ceil(N_EDGES/NBLK)

typedef unsigned int uint;

// ---------------- bf16 helpers ----------------

__device__ __forceinline__ uint bfrn(float x) {  // fp32 -> bf16 bits (RN)
  uint u = __float_as_uint(x);
  u += 0x7fffu + ((u >> 16) & 1u);
  return u >> 16;
}
__device__ __forceinline__ uint bfpack(float a, float b) {
  return bfrn(a) | (bfrn(b) << 16);
}

// ---------------- pass 1: per-block bucket histogram + global degree ----------------

__global__ __launch_bounds__(256) void hist_deg_k(const int* __restrict__ ei,
                                                  int* __restrict__ hist,
                                                  int* __restrict__ deg) {
  __shared__ int lh[NB];
  for (int i = threadIdx.x; i < NB; i += 256) lh[i] = 0;
  __syncthreads();
  int b = blockIdx.x;
  int e1 = min(b * CHUNK + CHUNK, N_EDGES);
  for (int e = b * CHUNK + threadIdx.x; e < e1; e += 256) {
    int r = ei[e];
    atomicAdd(&lh[r >> 8], 1);
    atomicAdd(&deg[r], 1);
  }
  __syncthreads();
  for (int i = threadIdx.x; i < NB; i += 256) hist[b * NB + i] = lh[i];
}

// ---------------- off[] scan over deg (dinv fused) ----------------

__global__ __launch_bounds__(1024) void scan_block_k(const int* __restrict__ deg,
                                                     int* __restrict__ incl,
                                                     int* __restrict__ bsums,
                                                     float* __restrict__ dinv) {
  __shared__ int s[1024];
  int i = blockIdx.x * 1024 + threadIdx.x;
  int v = (i < N_NODES) ? deg[i] : 0;
  if (i < N_NODES) dinv[i] = rsqrtf((float)v + 1.0f);  // +1 = self-loop
  s[threadIdx.x] = v;
  __syncthreads();
  for (int d = 1; d < 1024; d <<= 1) {
    int t = (threadIdx.x >= d) ? s[threadIdx.x - d] : 0;
    __syncthreads();
    s[threadIdx.x] += t;
    __syncthreads();
  }
  if (i < N_NODES) incl[i] = s[threadIdx.x];
  if (threadIdx.x == 1023) bsums[blockIdx.x] = s[1023];
}

__global__ __launch_bounds__(128) void scan_bsums_k(int* bsums, int nb) {
  __shared__ int s[128];
  int v = (threadIdx.x < nb) ? bsums[threadIdx.x] : 0;
  s[threadIdx.x] = v;
  __syncthreads();
  for (int d = 1; d < 128; d <<= 1) {
    int t = (threadIdx.x >= d) ? s[threadIdx.x - d] : 0;
    __syncthreads();
    s[threadIdx.x] += t;
    __syncthreads();
  }
  if (threadIdx.x < nb) bsums[threadIdx.x] = s[threadIdx.x] - v;  // exclusive
}

__global__ __launch_bounds__(256) void finalize_off_k(const int* __restrict__ incl,
                                                      const int* __restrict__ bsums,
                                                      int* __restrict__ off) {
  int i = blockIdx.x * 256 + threadIdx.x;
  if (i < N_NODES) off[i + 1] = incl[i] + bsums[i >> 10];
  if (i == 0) off[0] = 0;
}

// ---------------- pass 2: column-scan of histograms -> per-(block,bucket) write pos ----

__global__ __launch_bounds__(64) void scan_hist_k(const int* __restrict__ hist,
                                                  const int* __restrict__ off,
                                                  int* __restrict__ pos) {
  int k = blockIdx.x, lane = threadIdx.x;
  int carry = off[k << 8];  // bucket start in CSR space
  for (int c = 0; c < 4; c++) {
    int b = c * 64 + lane;
    int v = hist[b * NB + k];
    int x = v;
    for (int d = 1; d < 64; d <<= 1) {
      int t = __shfl_up(x, d);
      if (lane >= d) x += t;
    }
    pos[b * NB + k] = carry + x - v;  // exclusive
    carry += __shfl(x, 63);
  }
}

// ---------------- pass 3: stable binned scatter ----------------

__global__ __launch_bounds__(256) void bin_k(const int* __restrict__ ei,
                                             const int* __restrict__ pos,
                                             unsigned* __restrict__ binbuf) {
  __shared__ int lcur[NB];
  int b = blockIdx.x;
  for (int i = threadIdx.x; i < NB; i += 256) lcur[i] = pos[b * NB + i];
  __syncthreads();
  int e1 = min(b * CHUNK + CHUNK, N_EDGES);
  for (int e = b * CHUNK + threadIdx.x; e < e1; e += 256) {
    int r = ei[e];
    int c = ei[N_EDGES + e];
    int p = atomicAdd(&lcur[r >> 8], 1);
    binbuf[p] = ((unsigned)(r & 255) << 24) | (unsigned)c;  // c < 2^17 fits
  }
}

// ---------------- pass 4: within-bucket placement + coef fuse ----------------

__global__ __launch_bounds__(256) void csr_k(const unsigned* __restrict__ binbuf,
                                             const int* __restrict__ off,
                                             const float* __restrict__ dinv,
                                             int2* __restrict__ cc) {
  __shared__ int cur[256];
  int b = blockIdx.x, row0 = b << 8;
  int nrows = min(256, N_NODES - row0);
  if (threadIdx.x < nrows) cur[threadIdx.x] = off[row0 + threadIdx.x];
  __syncthreads();
  int e0 = off[row0];
  int e1 = off[min(row0 + 256, N_NODES)];
  for (int e = e0 + threadIdx.x; e < e1; e += 256) {
    unsigned u = binbuf[e];
    int rl = u >> 24;
    int c = (int)(u & 0xFFFFFFu);
    int slot = atomicAdd(&cur[rl], 1);
    float w = dinv[row0 + rl] * dinv[c];
    cc[slot] = make_int2(c, __float_as_int(w));
  }
}

// ---------------- W01 = W0 @ W1 (128x128x128, tiny) ----------------

__global__ __launch_bounds__(256) void w01_k(const float* __restrict__ W0,
                                             const float* __restrict__ W1,
                                             float* __restrict__ W01) {
  int g = blockIdx.x * 256 + threadIdx.x;  // 16384 outputs
  int i = g >> 7, j = g & 127;
  float s = 0.f;
  for (int k = 0; k < 128; k++) s = fmaf(W0[i * 128 + k], W1[k * 128 + j], s);
  W01[g] = s;
}

// ---------------- prop over bf16 X (128 feat), fp32 accumulate, one wave/node ----------

template <bool RELU>
__global__ __launch_bounds__(256) void prop128h_k(const uint* __restrict__ X,  // bf16x2
                                                  float* __restrict__ Y,
                                                  const int* __restrict__ off,
                                                  const int2* __restrict__ cc,
                                                  const float* __restrict__ dinv) {
  int node = blockIdx.x * 4 + (threadIdx.x >> 6);
  if (node >= N_NODES) return;
  int lane = threadIdx.x & 63;
  float di = dinv[node];
  float sc = di * di;
  uint s = X[(size_t)node * 64 + lane];
  float2 acc;
  acc.x = __uint_as_float(s << 16) * sc;
  acc.y = __uint_as_float(s & 0xffff0000u) * sc;
  int e = off[node], e1 = off[node + 1];
  for (; e + 7 < e1; e += 8) {
    int2 q[8];
    uint v[8];
#pragma unroll
    for (int j = 0; j < 8; j++) q[j] = cc[e + j];
#pragma unroll
    for (int j = 0; j < 8; j++) v[j] = X[(size_t)q[j].x * 64 + lane];
#pragma unroll
    for (int j = 0; j < 8; j++) {
      float w = __int_as_float(q[j].y);
      acc.x = fmaf(__uint_as_float(v[j] << 16), w, acc.x);
      acc.y = fmaf(__uint_as_float(v[j] & 0xffff0000u), w, acc.y);
    }
  }
  for (; e < e1; e++) {
    int2 q = cc[e];
    uint v = X[(size_t)q.x * 64 + lane];
    float w = __int_as_float(q.y);
    acc.x = fmaf(__uint_as_float(v << 16), w, acc.x);
    acc.y = fmaf(__uint_as_float(v & 0xffff0000u), w, acc.y);
  }
  if (RELU) { acc.x = fmaxf(acc.x, 0.f); acc.y = fmaxf(acc.y, 0.f); }
  ((float2*)Y)[(size_t)node * 64 + lane] = acc;
}

// ---------------- prop over fp32 X (64 feat), one wave/node ----------------

__global__ __launch_bounds__(256) void prop64_k(const float* __restrict__ X,
                                                float* __restrict__ Y,
                                                const int* __restrict__ off,
                                                const int2* __restrict__ cc,
                                                const float* __restrict__ dinv) {
  int node = blockIdx.x * 4 + (threadIdx.x >> 6);
  if (node >= N_NODES) return;
  int lane = threadIdx.x & 63;
  float di = dinv[node];
  float acc = X[(size_t)node * 64 + lane] * di * di;
  int e = off[node], e1 = off[node + 1];
  for (; e + 7 < e1; e += 8) {
    int2 q[8];
    float v[8];
#pragma unroll
    for (int j = 0; j < 8; j++) q[j] = cc[e + j];
#pragma unroll
    for (int j = 0; j < 8; j++) v[j] = X[(size_t)q[j].x * 64 + lane];
#pragma unroll
    for (int j = 0; j < 8; j++) acc = fmaf(v[j], __int_as_float(q[j].y), acc);
  }
  for (; e < e1; e++) {
    int2 q = cc[e];
    acc = fmaf(X[(size_t)q.x * 64 + lane], __int_as_float(q.y), acc);
  }
  Y[(size_t)node * 64 + lane] = acc;
}

// ---------------- fp32 GEMM, K=128; A-tile in LDS (32 KB); optional bf16 output ----

template <int FOUT, bool RELU, bool BF16OUT>
__global__ __launch_bounds__(256) void gemm_k128(const float* __restrict__ A,
                                                 const float* __restrict__ W,
                                                 void* __restrict__ Cv) {
  __shared__ float Al[64 * 128];      // 32 KB
  constexpr int TC = FOUT / 4;        // 32 or 16
  constexpr int R = 64 / (256 / TC);  // 8 or 4
  int tid = threadIdx.x;
  int row0 = blockIdx.x * 64;
  for (int i = tid; i < 64 * 32; i += 256) {
    int r = i >> 5;
    int gr = row0 + r;
    float4 v = make_float4(0.f, 0.f, 0.f, 0.f);
    if (gr < N_NODES) v = ((const float4*)A)[(size_t)gr * 32 + (i & 31)];
    ((float4*)Al)[i] = v;
  }
  __syncthreads();
  int tc = tid % TC, tr = tid / TC;
  int c0 = tc * 4, r0 = tr * R;
  float acc[R][4];
#pragma unroll
  for (int r = 0; r < R; r++)
#pragma unroll
    for (int c = 0; c < 4; c++) acc[r][c] = 0.f;

  for (int k = 0; k < 128; k += 4) {
    float4 w[4];
#pragma unroll
    for (int kk = 0; kk < 4; kk++) w[kk] = *(const float4*)&W[(k + kk) * FOUT + c0];
    float4 a[R];
#pragma unroll
    for (int r = 0; r < R; r++) a[r] = *(const float4*)&Al[(r0 + r) * 128 + k];
#pragma unroll
    for (int kk = 0; kk < 4; kk++) {
#pragma unroll
      for (int r = 0; r < R; r++) {
        float av = (kk == 0) ? a[r].x : (kk == 1) ? a[r].y : (kk == 2) ? a[r].z : a[r].w;
        acc[r][0] = fmaf(av, w[kk].x, acc[r][0]);
        acc[r][1] = fmaf(av, w[kk].y, acc[r][1]);
        acc[r][2] = fmaf(av, w[kk].z, acc[r][2]);
        acc[r][3] = fmaf(av, w[kk].w, acc[r][3]);
      }
    }
  }
#pragma unroll
  for (int r = 0; r < R; r++) {
    int gr = row0 + r0 + r;
    if (gr < N_NODES) {
      float x0v = acc[r][0], x1v = acc[r][1], x2v = acc[r][2], x3v = acc[r][3];
      if (RELU) {
        x0v = fmaxf(x0v, 0.f); x1v = fmaxf(x1v, 0.f);
        x2v = fmaxf(x2v, 0.f); x3v = fmaxf(x3v, 0.f);
      }
      if (BF16OUT) {
        uint2 p;
        p.x = bfpack(x0v, x1v);
        p.y = bfpack(x2v, x3v);
        ((uint2*)Cv)[(size_t)gr * (FOUT / 4) + tc] = p;
      } else {
        float4 v;
        v.x = x0v; v.y = x1v; v.z = x2v; v.w = x3v;
        ((float4*)Cv)[(size_t)gr * (FOUT / 4) + tc] = v;
      }
    }
  }
}

// ---------------- launch ----------------
// Pipeline (uses (PX)W == P(XW)):
//   W01 = W0@W1
//   x0b = bf16(feat @ W01)
//   x1  = relu(P x0b)          (fp32)
//   t2  = x1 @ W2              (fp32, aliases x0b buffer region)
//   out = P t2

extern "C" void kernel_launch(void* const* d_in, const int* in_sizes, int n_in,
                              void* d_out, int out_size, void* d_ws, size_t ws_size,
                              hipStream_t stream) {
  const float* feat = (const float*)d_in[0];
  const int* ei = (const int*)d_in[1];  // int32 per harness contract
  const float* W0 = (const float*)d_in[2];
  const float* W1 = (const float*)d_in[3];
  const float* W2 = (const float*)d_in[4];
  float* out = (float*)d_out;

  char* ws = (char*)d_ws;
  uint* x0b = (uint*)ws;       ws += (size_t)N_NODES * 128 * 2;   // bf16, 25.6 MB
  // t2 (fp32 N x 64 = 25.6 MB) aliases x0b exactly
  float* x1 = (float*)ws;      ws += (size_t)N_NODES * 128 * 4;   // binbuf aliases x1
  int2* cc = (int2*)ws;        ws += (size_t)N_EDGES * 8;
  float* dinv = (float*)ws;    ws += (size_t)N_NODES * 4;
  int* deg = (int*)ws;         ws += (size_t)N_NODES * 4;
  int* incl = (int*)ws;        ws += (size_t)N_NODES * 4;
  int* off = (int*)ws;         ws += (size_t)(N_NODES + 2) * 4;
  int* bsums = (int*)ws;       ws += 128 * 4;
  int* hist = (int*)ws;        ws += (size_t)NBLK * NB * 4;
  int* pos = (int*)ws;         ws += (size_t)NBLK * NB * 4;
  float* W01 = (float*)ws;     ws += 128 * 128 * 4;
  unsigned* binbuf = (unsigned*)x1;  // 6.4 MB, dead before x1 is written
  float* t2 = (float*)x0b;           // x0b dead after prop128h

  const int nb_scan = (N_NODES + 1023) / 1024;  // 98

  hipMemsetAsync(deg, 0, (size_t)N_NODES * 4, stream);
  hist_deg_k<<<NBLK, 256, 0, stream>>>(ei, hist, deg);
  scan_block_k<<<nb_scan, 1024, 0, stream>>>(deg, incl, bsums, dinv);
  scan_bsums_k<<<1, 128, 0, stream>>>(bsums, nb_scan);
  finalize_off_k<<<(N_NODES + 255) / 256, 256, 0, stream>>>(incl, bsums, off);
  scan_hist_k<<<NB, 64, 0, stream>>>(hist, off, pos);
  bin_k<<<NBLK, 256, 0, stream>>>(ei, pos, binbuf);
  csr_k<<<NB, 256, 0, stream>>>(binbuf, off, dinv, cc);

  w01_k<<<64, 256, 0, stream>>>(W0, W1, W01);
  gemm_k128<128, false, true><<<(N_NODES + 63) / 64, 256, 0, stream>>>(feat, W01, x0b);
  prop128h_k<true><<<(N_NODES + 3) / 4, 256, 0, stream>>>(x0b, x1, off, cc, dinv);
  gemm_k128<64, false, false><<<(N_NODES + 63) / 64, 256, 0, stream>>>(x1, W2, t2);
  prop64_k<<<(N_NODES + 3) / 4, 256, 0, stream>>>(t2, out, off, cc, dinv);
}

// Round 5
// 291.241 us; speedup vs baseline: 2.4996x; 1.2390x over previous
//
#include <hip/hip_runtime.h>

#define N_NODES 100000
#define N_EDGES 1600000
#define NB 391            // ceil(N_NODES/256) row-buckets of 256 rows
#define NBLK 256          // blocks for binning passes
#define CHUNK 6250        // ceil(N_EDGES/NBLK)

typedef unsigned int uint;

// ---------------- bf16 helpers ----------------

__device__ __forceinline__ uint bfrn(float x) {  // fp32 -> bf16 bits (RN)
  uint u = __float_as_uint(x);
  u += 0x7fffu + ((u >> 16) & 1u);
  return u >> 16;
}
__device__ __forceinline__ uint bfpack(float a, float b) {
  return bfrn(a) | (bfrn(b) << 16);
}

// ---------------- pass 1: per-block bucket histogram (LDS only, no global atomics) ----

__global__ __launch_bounds__(256) void hist_k(const int* __restrict__ ei,
                                              int* __restrict__ hist) {
  __shared__ int lh[NB];
  for (int i = threadIdx.x; i < NB; i += 256) lh[i] = 0;
  __syncthreads();
  int b = blockIdx.x;
  int e1 = min(b * CHUNK + CHUNK, N_EDGES);
  for (int e = b * CHUNK + threadIdx.x; e < e1; e += 256) {
    atomicAdd(&lh[ei[e] >> 8], 1);
  }
  __syncthreads();
  for (int i = threadIdx.x; i < NB; i += 256) hist[b * NB + i] = lh[i];
}

// ---------------- pass 2: per-bucket column scan (local prefix) + bucket totals ----

__global__ __launch_bounds__(64) void scan_hist_k(const int* __restrict__ hist,
                                                  int* __restrict__ pos,
                                                  int* __restrict__ coltot) {
  int k = blockIdx.x, lane = threadIdx.x;
  int carry = 0;
  for (int c = 0; c < 4; c++) {
    int b = c * 64 + lane;
    int v = hist[b * NB + k];
    int x = v;
    for (int d = 1; d < 64; d <<= 1) {
      int t = __shfl_up(x, d);
      if (lane >= d) x += t;
    }
    pos[b * NB + k] = carry + x - v;  // exclusive within bucket
    carry += __shfl(x, 63);
  }
  if (lane == 0) coltot[k] = carry;
}

// ---------------- pass 2b: exclusive scan of bucket totals -> bucket bases ----------

__global__ __launch_bounds__(512) void base_scan_k(const int* __restrict__ coltot,
                                                   int* __restrict__ base) {
  __shared__ int s[512];
  int v = (threadIdx.x < NB) ? coltot[threadIdx.x] : 0;
  s[threadIdx.x] = v;
  __syncthreads();
  for (int d = 1; d < 512; d <<= 1) {
    int t = (threadIdx.x >= d) ? s[threadIdx.x - d] : 0;
    __syncthreads();
    s[threadIdx.x] += t;
    __syncthreads();
  }
  if (threadIdx.x < NB) base[threadIdx.x] = s[threadIdx.x] - v;  // exclusive
}

// ---------------- pass 3: stable binned scatter ----------------

__global__ __launch_bounds__(256) void bin_k(const int* __restrict__ ei,
                                             const int* __restrict__ pos,
                                             const int* __restrict__ base,
                                             unsigned* __restrict__ binbuf) {
  __shared__ int lcur[NB];
  int b = blockIdx.x;
  for (int i = threadIdx.x; i < NB; i += 256) lcur[i] = pos[b * NB + i] + base[i];
  __syncthreads();
  int e1 = min(b * CHUNK + CHUNK, N_EDGES);
  for (int e = b * CHUNK + threadIdx.x; e < e1; e += 256) {
    int r = ei[e];
    int c = ei[N_EDGES + e];
    int p = atomicAdd(&lcur[r >> 8], 1);
    binbuf[p] = ((unsigned)(r & 255) << 24) | (unsigned)c;  // c < 2^17 fits
  }
}

// ---------------- pass 4: per-bucket LDS histogram -> deg/off/dinv ----------------

__global__ __launch_bounds__(256) void bucket_off_k(const unsigned* __restrict__ binbuf,
                                                    const int* __restrict__ base,
                                                    const int* __restrict__ coltot,
                                                    int* __restrict__ off,
                                                    float* __restrict__ dinv) {
  __shared__ int cnt[256];
  __shared__ int sc[256];
  int k = blockIdx.x, row0 = k << 8;
  cnt[threadIdx.x] = 0;
  __syncthreads();
  int e0 = base[k], e1 = e0 + coltot[k];
  for (int e = e0 + threadIdx.x; e < e1; e += 256) atomicAdd(&cnt[binbuf[e] >> 24], 1);
  __syncthreads();
  int v = cnt[threadIdx.x];
  sc[threadIdx.x] = v;
  __syncthreads();
  for (int d = 1; d < 256; d <<= 1) {
    int t = (threadIdx.x >= d) ? sc[threadIdx.x - d] : 0;
    __syncthreads();
    sc[threadIdx.x] += t;
    __syncthreads();
  }
  int row = row0 + threadIdx.x;
  if (row < N_NODES) {
    off[row] = e0 + sc[threadIdx.x] - v;  // exclusive prefix
    dinv[row] = rsqrtf((float)v + 1.0f);  // +1 = self-loop
  }
  if (k == NB - 1 && threadIdx.x == 0) off[N_NODES] = N_EDGES;
}

// ---------------- pass 5: within-bucket placement + coef fuse ----------------

__global__ __launch_bounds__(256) void csr_k(const unsigned* __restrict__ binbuf,
                                             const int* __restrict__ off,
                                             const float* __restrict__ dinv,
                                             int2* __restrict__ cc) {
  __shared__ int cur[256];
  int b = blockIdx.x, row0 = b << 8;
  int nrows = min(256, N_NODES - row0);
  if (threadIdx.x < nrows) cur[threadIdx.x] = off[row0 + threadIdx.x];
  __syncthreads();
  int e0 = off[row0];
  int e1 = off[min(row0 + 256, N_NODES)];
  for (int e = e0 + threadIdx.x; e < e1; e += 256) {
    unsigned u = binbuf[e];
    int rl = u >> 24;
    int c = (int)(u & 0xFFFFFFu);
    int slot = atomicAdd(&cur[rl], 1);
    float w = dinv[row0 + rl] * dinv[c];
    cc[slot] = make_int2(c, __float_as_int(w));
  }
}

// ---------------- W01 = W0 @ W1 (128x128x128, tiny) ----------------

__global__ __launch_bounds__(256) void w01_k(const float* __restrict__ W0,
                                             const float* __restrict__ W1,
                                             float* __restrict__ W01) {
  int g = blockIdx.x * 256 + threadIdx.x;  // 16384 outputs
  int i = g >> 7, j = g & 127;
  float s = 0.f;
  for (int k = 0; k < 128; k++) s = fmaf(W0[i * 128 + k], W1[k * 128 + j], s);
  W01[g] = s;
}

// ---------------- prop over bf16 X (128 feat), fp32 accumulate, one wave/node ----------

template <bool RELU>
__global__ __launch_bounds__(256) void prop128h_k(const uint* __restrict__ X,  // bf16x2
                                                  float* __restrict__ Y,
                                                  const int* __restrict__ off,
                                                  const int2* __restrict__ cc,
                                                  const float* __restrict__ dinv) {
  int node = blockIdx.x * 4 + (threadIdx.x >> 6);
  if (node >= N_NODES) return;
  int lane = threadIdx.x & 63;
  float di = dinv[node];
  float sc = di * di;
  uint s = X[(size_t)node * 64 + lane];
  float2 acc;
  acc.x = __uint_as_float(s << 16) * sc;
  acc.y = __uint_as_float(s & 0xffff0000u) * sc;
  int e = off[node], e1 = off[node + 1];
  for (; e + 7 < e1; e += 8) {
    int2 q[8];
    uint v[8];
#pragma unroll
    for (int j = 0; j < 8; j++) q[j] = cc[e + j];
#pragma unroll
    for (int j = 0; j < 8; j++) v[j] = X[(size_t)q[j].x * 64 + lane];
#pragma unroll
    for (int j = 0; j < 8; j++) {
      float w = __int_as_float(q[j].y);
      acc.x = fmaf(__uint_as_float(v[j] << 16), w, acc.x);
      acc.y = fmaf(__uint_as_float(v[j] & 0xffff0000u), w, acc.y);
    }
  }
  for (; e < e1; e++) {
    int2 q = cc[e];
    uint v = X[(size_t)q.x * 64 + lane];
    float w = __int_as_float(q.y);
    acc.x = fmaf(__uint_as_float(v << 16), w, acc.x);
    acc.y = fmaf(__uint_as_float(v & 0xffff0000u), w, acc.y);
  }
  if (RELU) { acc.x = fmaxf(acc.x, 0.f); acc.y = fmaxf(acc.y, 0.f); }
  ((float2*)Y)[(size_t)node * 64 + lane] = acc;
}

// ---------------- prop over bf16 X (64 feat), fp32 accumulate, one wave/node ----------

__global__ __launch_bounds__(256) void prop64h_k(const unsigned short* __restrict__ X,
                                                 float* __restrict__ Y,
                                                 const int* __restrict__ off,
                                                 const int2* __restrict__ cc,
                                                 const float* __restrict__ dinv) {
  int node = blockIdx.x * 4 + (threadIdx.x >> 6);
  if (node >= N_NODES) return;
  int lane = threadIdx.x & 63;
  float di = dinv[node];
  uint s = (uint)X[(size_t)node * 64 + lane] << 16;
  float acc = __uint_as_float(s) * di * di;
  int e = off[node], e1 = off[node + 1];
  for (; e + 7 < e1; e += 8) {
    int2 q[8];
    uint v[8];
#pragma unroll
    for (int j = 0; j < 8; j++) q[j] = cc[e + j];
#pragma unroll
    for (int j = 0; j < 8; j++) v[j] = (uint)X[(size_t)q[j].x * 64 + lane] << 16;
#pragma unroll
    for (int j = 0; j < 8; j++) acc = fmaf(__uint_as_float(v[j]), __int_as_float(q[j].y), acc);
  }
  for (; e < e1; e++) {
    int2 q = cc[e];
    uint v = (uint)X[(size_t)q.x * 64 + lane] << 16;
    acc = fmaf(__uint_as_float(v), __int_as_float(q.y), acc);
  }
  Y[(size_t)node * 64 + lane] = acc;
}

// ---------------- fp32 GEMM, K=128; A-tile in LDS (32 KB); optional bf16 output ----

template <int FOUT, bool RELU, bool BF16OUT>
__global__ __launch_bounds__(256) void gemm_k128(const float* __restrict__ A,
                                                 const float* __restrict__ W,
                                                 void* __restrict__ Cv) {
  __shared__ float Al[64 * 128];      // 32 KB
  constexpr int TC = FOUT / 4;        // 32 or 16
  constexpr int R = 64 / (256 / TC);  // 8 or 4
  int tid = threadIdx.x;
  int row0 = blockIdx.x * 64;
  for (int i = tid; i < 64 * 32; i += 256) {
    int r = i >> 5;
    int gr = row0 + r;
    float4 v = make_float4(0.f, 0.f, 0.f, 0.f);
    if (gr < N_NODES) v = ((const float4*)A)[(size_t)gr * 32 + (i & 31)];
    ((float4*)Al)[i] = v;
  }
  __syncthreads();
  int tc = tid % TC, tr = tid / TC;
  int c0 = tc * 4, r0 = tr * R;
  float acc[R][4];
#pragma unroll
  for (int r = 0; r < R; r++)
#pragma unroll
    for (int c = 0; c < 4; c++) acc[r][c] = 0.f;

  for (int k = 0; k < 128; k += 4) {
    float4 w[4];
#pragma unroll
    for (int kk = 0; kk < 4; kk++) w[kk] = *(const float4*)&W[(k + kk) * FOUT + c0];
    float4 a[R];
#pragma unroll
    for (int r = 0; r < R; r++) a[r] = *(const float4*)&Al[(r0 + r) * 128 + k];
#pragma unroll
    for (int kk = 0; kk < 4; kk++) {
#pragma unroll
      for (int r = 0; r < R; r++) {
        float av = (kk == 0) ? a[r].x : (kk == 1) ? a[r].y : (kk == 2) ? a[r].z : a[r].w;
        acc[r][0] = fmaf(av, w[kk].x, acc[r][0]);
        acc[r][1] = fmaf(av, w[kk].y, acc[r][1]);
        acc[r][2] = fmaf(av, w[kk].z, acc[r][2]);
        acc[r][3] = fmaf(av, w[kk].w, acc[r][3]);
      }
    }
  }
#pragma unroll
  for (int r = 0; r < R; r++) {
    int gr = row0 + r0 + r;
    if (gr < N_NODES) {
      float x0v = acc[r][0], x1v = acc[r][1], x2v = acc[r][2], x3v = acc[r][3];
      if (RELU) {
        x0v = fmaxf(x0v, 0.f); x1v = fmaxf(x1v, 0.f);
        x2v = fmaxf(x2v, 0.f); x3v = fmaxf(x3v, 0.f);
      }
      if (BF16OUT) {
        uint2 p;
        p.x = bfpack(x0v, x1v);
        p.y = bfpack(x2v, x3v);
        ((uint2*)Cv)[(size_t)gr * (FOUT / 4) + tc] = p;
      } else {
        float4 v;
        v.x = x0v; v.y = x1v; v.z = x2v; v.w = x3v;
        ((float4*)Cv)[(size_t)gr * (FOUT / 4) + tc] = v;
      }
    }
  }
}

// ---------------- launch ----------------
// Pipeline (uses (PX)W == P(XW)):
//   W01 = W0@W1
//   x0b = bf16(feat @ W01)
//   x1  = relu(P x0b)          (fp32)
//   t2b = bf16(x1 @ W2)        (aliases x0b)
//   out = P t2b                (fp32 out)

extern "C" void kernel_launch(void* const* d_in, const int* in_sizes, int n_in,
                              void* d_out, int out_size, void* d_ws, size_t ws_size,
                              hipStream_t stream) {
  const float* feat = (const float*)d_in[0];
  const int* ei = (const int*)d_in[1];  // int32 per harness contract
  const float* W0 = (const float*)d_in[2];
  const float* W1 = (const float*)d_in[3];
  const float* W2 = (const float*)d_in[4];
  float* out = (float*)d_out;

  char* ws = (char*)d_ws;
  uint* x0b = (uint*)ws;       ws += (size_t)N_NODES * 128 * 2;   // bf16, 25.6 MB
  float* x1 = (float*)ws;      ws += (size_t)N_NODES * 128 * 4;   // binbuf aliases x1
  int2* cc = (int2*)ws;        ws += (size_t)N_EDGES * 8;
  float* dinv = (float*)ws;    ws += (size_t)N_NODES * 4;
  int* off = (int*)ws;         ws += (size_t)(N_NODES + 2) * 4;
  int* hist = (int*)ws;        ws += (size_t)NBLK * NB * 4;
  int* pos = (int*)ws;         ws += (size_t)NBLK * NB * 4;
  int* coltot = (int*)ws;      ws += (size_t)NB * 4;
  int* base = (int*)ws;        ws += (size_t)NB * 4;
  float* W01 = (float*)ws;     ws += 128 * 128 * 4;
  unsigned* binbuf = (unsigned*)x1;        // 6.4 MB, dead before x1 is written
  unsigned short* t2b = (unsigned short*)x0b;  // bf16 N x 64, x0b dead after prop128h

  hist_k<<<NBLK, 256, 0, stream>>>(ei, hist);
  scan_hist_k<<<NB, 64, 0, stream>>>(hist, pos, coltot);
  base_scan_k<<<1, 512, 0, stream>>>(coltot, base);
  bin_k<<<NBLK, 256, 0, stream>>>(ei, pos, base, binbuf);
  bucket_off_k<<<NB, 256, 0, stream>>>(binbuf, base, coltot, off, dinv);
  csr_k<<<NB, 256, 0, stream>>>(binbuf, off, dinv, cc);

  w01_k<<<64, 256, 0, stream>>>(W0, W1, W01);
  gemm_k128<128, false, true><<<(N_NODES + 63) / 64, 256, 0, stream>>>(feat, W01, x0b);
  prop128h_k<true><<<(N_NODES + 3) / 4, 256, 0, stream>>>(x0b, x1, off, cc, dinv);
  gemm_k128<64, false, true><<<(N_NODES + 63) / 64, 256, 0, stream>>>(x1, W2, t2b);
  prop64h_k<<<(N_NODES + 3) / 4, 256, 0, stream>>>(t2b, out, off, cc, dinv);
}

// Round 6
// 287.050 us; speedup vs baseline: 2.5361x; 1.0146x over previous
//
#include <hip/hip_runtime.h>

#define N_NODES 100000
#define N_EDGES 1600000
#define NB 391            // ceil(N_NODES/256) row-buckets of 256 rows
#define NBLK 256          // blocks for binning passes
#define CHUNK 6250        // ceil(N_EDGES/NBLK)

typedef unsigned int uint;

// ---------------- bf16 helpers ----------------

__device__ __forceinline__ uint bfrn(float x) {  // fp32 -> bf16 bits (RN)
  uint u = __float_as_uint(x);
  u += 0x7fffu + ((u >> 16) & 1u);
  return u >> 16;
}
__device__ __forceinline__ uint bfpack(float a, float b) {
  return bfrn(a) | (bfrn(b) << 16);
}

// ---------------- pass 1: per-block bucket histogram (LDS only) ----------------

__global__ __launch_bounds__(256) void hist_k(const int* __restrict__ ei,
                                              int* __restrict__ hist) {
  __shared__ int lh[NB];
  for (int i = threadIdx.x; i < NB; i += 256) lh[i] = 0;
  __syncthreads();
  int b = blockIdx.x;
  int e1 = min(b * CHUNK + CHUNK, N_EDGES);
  for (int e = b * CHUNK + threadIdx.x; e < e1; e += 256) {
    atomicAdd(&lh[ei[e] >> 8], 1);
  }
  __syncthreads();
  for (int i = threadIdx.x; i < NB; i += 256) hist[b * NB + i] = lh[i];
}

// ---------------- pass 2: per-bucket column scan + bucket totals ----------------

__global__ __launch_bounds__(64) void scan_hist_k(const int* __restrict__ hist,
                                                  int* __restrict__ pos,
                                                  int* __restrict__ coltot) {
  int k = blockIdx.x, lane = threadIdx.x;
  int carry = 0;
  for (int c = 0; c < 4; c++) {
    int b = c * 64 + lane;
    int v = hist[b * NB + k];
    int x = v;
    for (int d = 1; d < 64; d <<= 1) {
      int t = __shfl_up(x, d);
      if (lane >= d) x += t;
    }
    pos[b * NB + k] = carry + x - v;  // exclusive within bucket
    carry += __shfl(x, 63);
  }
  if (lane == 0) coltot[k] = carry;
}

// ---------------- pass 2b: exclusive scan of bucket totals ----------------

__global__ __launch_bounds__(512) void base_scan_k(const int* __restrict__ coltot,
                                                   int* __restrict__ base) {
  __shared__ int s[512];
  int v = (threadIdx.x < NB) ? coltot[threadIdx.x] : 0;
  s[threadIdx.x] = v;
  __syncthreads();
  for (int d = 1; d < 512; d <<= 1) {
    int t = (threadIdx.x >= d) ? s[threadIdx.x - d] : 0;
    __syncthreads();
    s[threadIdx.x] += t;
    __syncthreads();
  }
  if (threadIdx.x < NB) base[threadIdx.x] = s[threadIdx.x] - v;  // exclusive
}

// ---------------- pass 3: stable binned scatter ----------------

__global__ __launch_bounds__(256) void bin_k(const int* __restrict__ ei,
                                             const int* __restrict__ pos,
                                             const int* __restrict__ base,
                                             unsigned* __restrict__ binbuf) {
  __shared__ int lcur[NB];
  int b = blockIdx.x;
  for (int i = threadIdx.x; i < NB; i += 256) lcur[i] = pos[b * NB + i] + base[i];
  __syncthreads();
  int e1 = min(b * CHUNK + CHUNK, N_EDGES);
  for (int e = b * CHUNK + threadIdx.x; e < e1; e += 256) {
    int r = ei[e];
    int c = ei[N_EDGES + e];
    int p = atomicAdd(&lcur[r >> 8], 1);
    binbuf[p] = ((unsigned)(r & 255) << 24) | (unsigned)c;  // c < 2^17 fits
  }
}

// ---------------- pass 4: per-bucket LDS histogram -> deg/off/dinv ----------------

__global__ __launch_bounds__(256) void bucket_off_k(const unsigned* __restrict__ binbuf,
                                                    const int* __restrict__ base,
                                                    const int* __restrict__ coltot,
                                                    int* __restrict__ off,
                                                    float* __restrict__ dinv) {
  __shared__ int cnt[256];
  __shared__ int sc[256];
  int k = blockIdx.x, row0 = k << 8;
  cnt[threadIdx.x] = 0;
  __syncthreads();
  int e0 = base[k], e1 = e0 + coltot[k];
  for (int e = e0 + threadIdx.x; e < e1; e += 256) atomicAdd(&cnt[binbuf[e] >> 24], 1);
  __syncthreads();
  int v = cnt[threadIdx.x];
  sc[threadIdx.x] = v;
  __syncthreads();
  for (int d = 1; d < 256; d <<= 1) {
    int t = (threadIdx.x >= d) ? sc[threadIdx.x - d] : 0;
    __syncthreads();
    sc[threadIdx.x] += t;
    __syncthreads();
  }
  int row = row0 + threadIdx.x;
  if (row < N_NODES) {
    off[row] = e0 + sc[threadIdx.x] - v;  // exclusive prefix
    dinv[row] = rsqrtf((float)v + 1.0f);  // +1 = self-loop
  }
  if (k == NB - 1 && threadIdx.x == 0) off[N_NODES] = N_EDGES;
}

// ---------------- pass 5: within-bucket placement + coef fuse ----------------

__global__ __launch_bounds__(256) void csr_k(const unsigned* __restrict__ binbuf,
                                             const int* __restrict__ off,
                                             const float* __restrict__ dinv,
                                             int2* __restrict__ cc) {
  __shared__ int cur[256];
  int b = blockIdx.x, row0 = b << 8;
  int nrows = min(256, N_NODES - row0);
  if (threadIdx.x < nrows) cur[threadIdx.x] = off[row0 + threadIdx.x];
  __syncthreads();
  int e0 = off[row0];
  int e1 = off[min(row0 + 256, N_NODES)];
  for (int e = e0 + threadIdx.x; e < e1; e += 256) {
    unsigned u = binbuf[e];
    int rl = u >> 24;
    int c = (int)(u & 0xFFFFFFu);
    int slot = atomicAdd(&cur[rl], 1);
    float w = dinv[row0 + rl] * dinv[c];
    cc[slot] = make_int2(c, __float_as_int(w));
  }
}

// ---------------- W01 = W0 @ W1 (128x128x128, tiny) ----------------

__global__ __launch_bounds__(256) void w01_k(const float* __restrict__ W0,
                                             const float* __restrict__ W1,
                                             float* __restrict__ W01) {
  int g = blockIdx.x * 256 + threadIdx.x;  // 16384 outputs
  int i = g >> 7, j = g & 127;
  float s = 0.f;
  for (int k = 0; k < 128; k++) s = fmaf(W0[i * 128 + k], W1[k * 128 + j], s);
  W01[g] = s;
}

// ---------------- prop over bf16 X (128 feat), fp32 accum, bf16 out ----------------

template <bool RELU>
__global__ __launch_bounds__(256) void prop128h_k(const uint* __restrict__ X,  // bf16x2
                                                  uint* __restrict__ Yb,       // bf16x2
                                                  const int* __restrict__ off,
                                                  const int2* __restrict__ cc,
                                                  const float* __restrict__ dinv) {
  int node = blockIdx.x * 4 + (threadIdx.x >> 6);
  if (node >= N_NODES) return;
  uint lane = threadIdx.x & 63u;
  float di = dinv[node];
  float sc = di * di;
  uint s = X[(uint)node * 64u + lane];
  float2 acc;
  acc.x = __uint_as_float(s << 16) * sc;
  acc.y = __uint_as_float(s & 0xffff0000u) * sc;
  int e = off[node], e1 = off[node + 1];
  for (; e + 7 < e1; e += 8) {
    int2 q[8];
    uint v[8];
#pragma unroll
    for (int j = 0; j < 8; j++) q[j] = cc[e + j];
#pragma unroll
    for (int j = 0; j < 8; j++) v[j] = X[(uint)q[j].x * 64u + lane];
#pragma unroll
    for (int j = 0; j < 8; j++) {
      float w = __int_as_float(q[j].y);
      acc.x = fmaf(__uint_as_float(v[j] << 16), w, acc.x);
      acc.y = fmaf(__uint_as_float(v[j] & 0xffff0000u), w, acc.y);
    }
  }
  for (; e < e1; e++) {
    int2 q = cc[e];
    uint v = X[(uint)q.x * 64u + lane];
    float w = __int_as_float(q.y);
    acc.x = fmaf(__uint_as_float(v << 16), w, acc.x);
    acc.y = fmaf(__uint_as_float(v & 0xffff0000u), w, acc.y);
  }
  if (RELU) { acc.x = fmaxf(acc.x, 0.f); acc.y = fmaxf(acc.y, 0.f); }
  Yb[(uint)node * 64u + lane] = bfpack(acc.x, acc.y);
}

// ---------------- prop over bf16 X (64 feat), fp32 accum + out ----------------

__global__ __launch_bounds__(256) void prop64h_k(const unsigned short* __restrict__ X,
                                                 float* __restrict__ Y,
                                                 const int* __restrict__ off,
                                                 const int2* __restrict__ cc,
                                                 const float* __restrict__ dinv) {
  int node = blockIdx.x * 4 + (threadIdx.x >> 6);
  if (node >= N_NODES) return;
  uint lane = threadIdx.x & 63u;
  float di = dinv[node];
  uint s = (uint)X[(uint)node * 64u + lane] << 16;
  float acc = __uint_as_float(s) * di * di;
  int e = off[node], e1 = off[node + 1];
  for (; e + 7 < e1; e += 8) {
    int2 q[8];
    uint v[8];
#pragma unroll
    for (int j = 0; j < 8; j++) q[j] = cc[e + j];
#pragma unroll
    for (int j = 0; j < 8; j++) v[j] = (uint)X[(uint)q[j].x * 64u + lane] << 16;
#pragma unroll
    for (int j = 0; j < 8; j++) acc = fmaf(__uint_as_float(v[j]), __int_as_float(q[j].y), acc);
  }
  for (; e < e1; e++) {
    int2 q = cc[e];
    uint v = (uint)X[(uint)q.x * 64u + lane] << 16;
    acc = fmaf(__uint_as_float(v), __int_as_float(q.y), acc);
  }
  Y[(uint)node * 64u + lane] = acc;
}

// ---------------- fp32-math GEMM, K=128; A fp32 or bf16; C fp32 or bf16 ----------

template <int FOUT, bool RELU, bool BF16OUT, bool ABF16>
__global__ __launch_bounds__(256) void gemm_k128(const void* __restrict__ Av,
                                                 const float* __restrict__ W,
                                                 void* __restrict__ Cv) {
  __shared__ float Al[64 * 128];      // 32 KB
  constexpr int TC = FOUT / 4;        // 32 or 16
  constexpr int R = 64 / (256 / TC);  // 8 or 4
  int tid = threadIdx.x;
  int row0 = blockIdx.x * 64;
  if (ABF16) {
    const uint2* Ab = (const uint2*)Av;  // 4 bf16 per uint2
    for (int i = tid; i < 64 * 32; i += 256) {
      int r = i >> 5, c = i & 31;
      int gr = row0 + r;
      float4 f = make_float4(0.f, 0.f, 0.f, 0.f);
      if (gr < N_NODES) {
        uint2 u = Ab[(uint)gr * 32u + c];
        f.x = __uint_as_float(u.x << 16);
        f.y = __uint_as_float(u.x & 0xffff0000u);
        f.z = __uint_as_float(u.y << 16);
        f.w = __uint_as_float(u.y & 0xffff0000u);
      }
      ((float4*)Al)[i] = f;
    }
  } else {
    const float4* Af = (const float4*)Av;
    for (int i = tid; i < 64 * 32; i += 256) {
      int r = i >> 5;
      int gr = row0 + r;
      float4 v = make_float4(0.f, 0.f, 0.f, 0.f);
      if (gr < N_NODES) v = Af[(uint)gr * 32u + (i & 31)];
      ((float4*)Al)[i] = v;
    }
  }
  __syncthreads();
  int tc = tid % TC, tr = tid / TC;
  int c0 = tc * 4, r0 = tr * R;
  float acc[R][4];
#pragma unroll
  for (int r = 0; r < R; r++)
#pragma unroll
    for (int c = 0; c < 4; c++) acc[r][c] = 0.f;

  for (int k = 0; k < 128; k += 4) {
    float4 w[4];
#pragma unroll
    for (int kk = 0; kk < 4; kk++) w[kk] = *(const float4*)&W[(k + kk) * FOUT + c0];
    float4 a[R];
#pragma unroll
    for (int r = 0; r < R; r++) a[r] = *(const float4*)&Al[(r0 + r) * 128 + k];
#pragma unroll
    for (int kk = 0; kk < 4; kk++) {
#pragma unroll
      for (int r = 0; r < R; r++) {
        float av = (kk == 0) ? a[r].x : (kk == 1) ? a[r].y : (kk == 2) ? a[r].z : a[r].w;
        acc[r][0] = fmaf(av, w[kk].x, acc[r][0]);
        acc[r][1] = fmaf(av, w[kk].y, acc[r][1]);
        acc[r][2] = fmaf(av, w[kk].z, acc[r][2]);
        acc[r][3] = fmaf(av, w[kk].w, acc[r][3]);
      }
    }
  }
#pragma unroll
  for (int r = 0; r < R; r++) {
    int gr = row0 + r0 + r;
    if (gr < N_NODES) {
      float x0v = acc[r][0], x1v = acc[r][1], x2v = acc[r][2], x3v = acc[r][3];
      if (RELU) {
        x0v = fmaxf(x0v, 0.f); x1v = fmaxf(x1v, 0.f);
        x2v = fmaxf(x2v, 0.f); x3v = fmaxf(x3v, 0.f);
      }
      if (BF16OUT) {
        uint2 p;
        p.x = bfpack(x0v, x1v);
        p.y = bfpack(x2v, x3v);
        ((uint2*)Cv)[(uint)gr * (FOUT / 4) + tc] = p;
      } else {
        float4 v;
        v.x = x0v; v.y = x1v; v.z = x2v; v.w = x3v;
        ((float4*)Cv)[(uint)gr * (FOUT / 4) + tc] = v;
      }
    }
  }
}

// ---------------- launch ----------------
// Pipeline (uses (PX)W == P(XW)):
//   W01 = W0@W1
//   x0b = bf16(feat @ W01)
//   x1b = bf16(relu(P x0b))
//   t2b = bf16(x1b @ W2)       (aliases x0b)
//   out = P t2b                (fp32 out)

extern "C" void kernel_launch(void* const* d_in, const int* in_sizes, int n_in,
                              void* d_out, int out_size, void* d_ws, size_t ws_size,
                              hipStream_t stream) {
  const float* feat = (const float*)d_in[0];
  const int* ei = (const int*)d_in[1];  // int32 per harness contract
  const float* W0 = (const float*)d_in[2];
  const float* W1 = (const float*)d_in[3];
  const float* W2 = (const float*)d_in[4];
  float* out = (float*)d_out;

  char* ws = (char*)d_ws;
  uint* x0b = (uint*)ws;       ws += (size_t)N_NODES * 128 * 2;   // bf16, 25.6 MB
  uint* x1b = (uint*)ws;       ws += (size_t)N_NODES * 128 * 2;   // bf16; binbuf aliases
  int2* cc = (int2*)ws;        ws += (size_t)N_EDGES * 8;
  float* dinv = (float*)ws;    ws += (size_t)N_NODES * 4;
  int* off = (int*)ws;         ws += (size_t)(N_NODES + 2) * 4;
  int* hist = (int*)ws;        ws += (size_t)NBLK * NB * 4;
  int* pos = (int*)ws;         ws += (size_t)NBLK * NB * 4;
  int* coltot = (int*)ws;      ws += (size_t)NB * 4;
  int* base = (int*)ws;        ws += (size_t)NB * 4;
  float* W01 = (float*)ws;     ws += 128 * 128 * 4;
  unsigned* binbuf = (unsigned*)x1b;           // 6.4 MB, dead before x1b written
  unsigned short* t2b = (unsigned short*)x0b;  // bf16 N x 64, x0b dead after prop128h

  hist_k<<<NBLK, 256, 0, stream>>>(ei, hist);
  scan_hist_k<<<NB, 64, 0, stream>>>(hist, pos, coltot);
  base_scan_k<<<1, 512, 0, stream>>>(coltot, base);
  bin_k<<<NBLK, 256, 0, stream>>>(ei, pos, base, binbuf);
  bucket_off_k<<<NB, 256, 0, stream>>>(binbuf, base, coltot, off, dinv);
  csr_k<<<NB, 256, 0, stream>>>(binbuf, off, dinv, cc);

  w01_k<<<64, 256, 0, stream>>>(W0, W1, W01);
  gemm_k128<128, false, true, false><<<(N_NODES + 63) / 64, 256, 0, stream>>>(feat, W01, x0b);
  prop128h_k<true><<<(N_NODES + 3) / 4, 256, 0, stream>>>(x0b, x1b, off, cc, dinv);
  gemm_k128<64, false, true, true><<<(N_NODES + 63) / 64, 256, 0, stream>>>(x1b, W2, t2b);
  prop64h_k<<<(N_NODES + 3) / 4, 256, 0, stream>>>(t2b, out, off, cc, dinv);
}

// Round 7
// 266.873 us; speedup vs baseline: 2.7278x; 1.0756x over previous
//
#include <hip/hip_runtime.h>

#define N_NODES 100000
#define N_EDGES 1600000
#define NB 391            // ceil(N_NODES/256) row-buckets of 256 rows
#define NBLK 256          // blocks for binning passes
#define CHUNK 6250        // ceil(N_EDGES/NBLK)

typedef unsigned int uint;

// ---------------- bf16 helpers ----------------

__device__ __forceinline__ uint bfrn(float x) {  // fp32 -> bf16 bits (RN)
  uint u = __float_as_uint(x);
  u += 0x7fffu + ((u >> 16) & 1u);
  return u >> 16;
}
__device__ __forceinline__ uint bfpack(float a, float b) {
  return bfrn(a) | (bfrn(b) << 16);
}
__device__ __forceinline__ float bflo(uint u) { return __uint_as_float(u << 16); }
__device__ __forceinline__ float bfhi(uint u) { return __uint_as_float(u & 0xffff0000u); }

// ---------------- pass 1: per-block bucket histogram (LDS only) ----------------

__global__ __launch_bounds__(256) void hist_k(const int* __restrict__ ei,
                                              int* __restrict__ hist) {
  __shared__ int lh[NB];
  for (int i = threadIdx.x; i < NB; i += 256) lh[i] = 0;
  __syncthreads();
  int b = blockIdx.x;
  int e1 = min(b * CHUNK + CHUNK, N_EDGES);
  for (int e = b * CHUNK + threadIdx.x; e < e1; e += 256) {
    atomicAdd(&lh[ei[e] >> 8], 1);
  }
  __syncthreads();
  for (int i = threadIdx.x; i < NB; i += 256) hist[b * NB + i] = lh[i];
}

// ---------------- pass 2: per-bucket column scan + bucket totals ----------------

__global__ __launch_bounds__(64) void scan_hist_k(const int* __restrict__ hist,
                                                  int* __restrict__ pos,
                                                  int* __restrict__ coltot) {
  int k = blockIdx.x, lane = threadIdx.x;
  int carry = 0;
  for (int c = 0; c < 4; c++) {
    int b = c * 64 + lane;
    int v = hist[b * NB + k];
    int x = v;
    for (int d = 1; d < 64; d <<= 1) {
      int t = __shfl_up(x, d);
      if (lane >= d) x += t;
    }
    pos[b * NB + k] = carry + x - v;  // exclusive within bucket
    carry += __shfl(x, 63);
  }
  if (lane == 0) coltot[k] = carry;
}

// ---------------- pass 2b: exclusive scan of bucket totals ----------------

__global__ __launch_bounds__(512) void base_scan_k(const int* __restrict__ coltot,
                                                   int* __restrict__ base) {
  __shared__ int s[512];
  int v = (threadIdx.x < NB) ? coltot[threadIdx.x] : 0;
  s[threadIdx.x] = v;
  __syncthreads();
  for (int d = 1; d < 512; d <<= 1) {
    int t = (threadIdx.x >= d) ? s[threadIdx.x - d] : 0;
    __syncthreads();
    s[threadIdx.x] += t;
    __syncthreads();
  }
  if (threadIdx.x < NB) base[threadIdx.x] = s[threadIdx.x] - v;  // exclusive
}

// ---------------- pass 3: stable binned scatter ----------------

__global__ __launch_bounds__(256) void bin_k(const int* __restrict__ ei,
                                             const int* __restrict__ pos,
                                             const int* __restrict__ base,
                                             unsigned* __restrict__ binbuf) {
  __shared__ int lcur[NB];
  int b = blockIdx.x;
  for (int i = threadIdx.x; i < NB; i += 256) lcur[i] = pos[b * NB + i] + base[i];
  __syncthreads();
  int e1 = min(b * CHUNK + CHUNK, N_EDGES);
  for (int e = b * CHUNK + threadIdx.x; e < e1; e += 256) {
    int r = ei[e];
    int c = ei[N_EDGES + e];
    int p = atomicAdd(&lcur[r >> 8], 1);
    binbuf[p] = ((unsigned)(r & 255) << 24) | (unsigned)c;  // c < 2^17 fits
  }
}

// ---------------- pass 4: per-bucket LDS histogram -> deg/off/dinv ----------------

__global__ __launch_bounds__(256) void bucket_off_k(const unsigned* __restrict__ binbuf,
                                                    const int* __restrict__ base,
                                                    const int* __restrict__ coltot,
                                                    int* __restrict__ off,
                                                    float* __restrict__ dinv) {
  __shared__ int cnt[256];
  __shared__ int sc[256];
  int k = blockIdx.x, row0 = k << 8;
  cnt[threadIdx.x] = 0;
  __syncthreads();
  int e0 = base[k], e1 = e0 + coltot[k];
  for (int e = e0 + threadIdx.x; e < e1; e += 256) atomicAdd(&cnt[binbuf[e] >> 24], 1);
  __syncthreads();
  int v = cnt[threadIdx.x];
  sc[threadIdx.x] = v;
  __syncthreads();
  for (int d = 1; d < 256; d <<= 1) {
    int t = (threadIdx.x >= d) ? sc[threadIdx.x - d] : 0;
    __syncthreads();
    sc[threadIdx.x] += t;
    __syncthreads();
  }
  int row = row0 + threadIdx.x;
  if (row < N_NODES) {
    off[row] = e0 + sc[threadIdx.x] - v;  // exclusive prefix
    dinv[row] = rsqrtf((float)v + 1.0f);  // +1 = self-loop
  }
  if (k == NB - 1 && threadIdx.x == 0) off[N_NODES] = N_EDGES;
}

// ---------------- pass 5: within-bucket placement + coef fuse ----------------

__global__ __launch_bounds__(256) void csr_k(const unsigned* __restrict__ binbuf,
                                             const int* __restrict__ off,
                                             const float* __restrict__ dinv,
                                             int2* __restrict__ cc) {
  __shared__ int cur[256];
  int b = blockIdx.x, row0 = b << 8;
  int nrows = min(256, N_NODES - row0);
  if (threadIdx.x < nrows) cur[threadIdx.x] = off[row0 + threadIdx.x];
  __syncthreads();
  int e0 = off[row0];
  int e1 = off[min(row0 + 256, N_NODES)];
  for (int e = e0 + threadIdx.x; e < e1; e += 256) {
    unsigned u = binbuf[e];
    int rl = u >> 24;
    int c = (int)(u & 0xFFFFFFu);
    int slot = atomicAdd(&cur[rl], 1);
    float w = dinv[row0 + rl] * dinv[c];
    cc[slot] = make_int2(c, __float_as_int(w));
  }
}

// ---------------- W01 = W0 @ W1 (128x128x128, tiny) ----------------

__global__ __launch_bounds__(256) void w01_k(const float* __restrict__ W0,
                                             const float* __restrict__ W1,
                                             float* __restrict__ W01) {
  int g = blockIdx.x * 256 + threadIdx.x;  // 16384 outputs
  int i = g >> 7, j = g & 127;
  float s = 0.f;
  for (int k = 0; k < 128; k++) s = fmaf(W0[i * 128 + k], W1[k * 128 + j], s);
  W01[g] = s;
}

// ---------------- prop, 128 bf16 feats, 2 edges/wave (32 lanes x uint2 each) ------
// Lane l: sub = l>>5 selects edge of the pair, o32 = l&31 selects 4 feats.
// acc feats = {4*o32 .. 4*o32+3}; halves merged via shfl_xor(32) at the end.

template <bool RELU>
__global__ __launch_bounds__(256) void prop128p_k(const uint2* __restrict__ X,  // bf16x4
                                                  uint2* __restrict__ Yb,       // bf16x4
                                                  const int* __restrict__ off,
                                                  const int2* __restrict__ cc,
                                                  const float* __restrict__ dinv) {
  int node = blockIdx.x * 4 + (threadIdx.x >> 6);
  if (node >= N_NODES) return;
  uint lane = threadIdx.x & 63u;
  uint sub = lane >> 5, o32 = lane & 31u;
  float di = dinv[node];
  float sc = di * di;
  uint2 s = X[(uint)node * 32u + o32];
  float4 acc = make_float4(0.f, 0.f, 0.f, 0.f);
  int e = off[node], e1 = off[node + 1];
  for (; e + 7 < e1; e += 8) {  // 4 pairs = 8 edges
    int2 q[4];
    uint2 v[4];
#pragma unroll
    for (int j = 0; j < 4; j++) q[j] = cc[e + 2 * j + sub];
#pragma unroll
    for (int j = 0; j < 4; j++) v[j] = X[(uint)q[j].x * 32u + o32];
#pragma unroll
    for (int j = 0; j < 4; j++) {
      float w = __int_as_float(q[j].y);
      acc.x = fmaf(bflo(v[j].x), w, acc.x);
      acc.y = fmaf(bfhi(v[j].x), w, acc.y);
      acc.z = fmaf(bflo(v[j].y), w, acc.z);
      acc.w = fmaf(bfhi(v[j].y), w, acc.w);
    }
  }
  for (; e + 1 < e1; e += 2) {  // remaining pairs
    int2 q = cc[e + sub];
    uint2 v = X[(uint)q.x * 32u + o32];
    float w = __int_as_float(q.y);
    acc.x = fmaf(bflo(v.x), w, acc.x);
    acc.y = fmaf(bfhi(v.x), w, acc.y);
    acc.z = fmaf(bflo(v.y), w, acc.z);
    acc.w = fmaf(bfhi(v.y), w, acc.w);
  }
  if (e < e1 && sub == 0) {  // single tail edge: half-wave only
    int2 q = cc[e];
    uint2 v = X[(uint)q.x * 32u + o32];
    float w = __int_as_float(q.y);
    acc.x = fmaf(bflo(v.x), w, acc.x);
    acc.y = fmaf(bfhi(v.x), w, acc.y);
    acc.z = fmaf(bflo(v.y), w, acc.z);
    acc.w = fmaf(bfhi(v.y), w, acc.w);
  }
  // merge edge-halves (partner lane has same o32, other sub)
  acc.x += __shfl_xor(acc.x, 32);
  acc.y += __shfl_xor(acc.y, 32);
  acc.z += __shfl_xor(acc.z, 32);
  acc.w += __shfl_xor(acc.w, 32);
  // self-loop term
  acc.x = fmaf(bflo(s.x), sc, acc.x);
  acc.y = fmaf(bfhi(s.x), sc, acc.y);
  acc.z = fmaf(bflo(s.y), sc, acc.z);
  acc.w = fmaf(bfhi(s.y), sc, acc.w);
  if (RELU) {
    acc.x = fmaxf(acc.x, 0.f); acc.y = fmaxf(acc.y, 0.f);
    acc.z = fmaxf(acc.z, 0.f); acc.w = fmaxf(acc.w, 0.f);
  }
  if (sub == 0) {
    uint2 p;
    p.x = bfpack(acc.x, acc.y);
    p.y = bfpack(acc.z, acc.w);
    Yb[(uint)node * 32u + o32] = p;
  }
}

// ---------------- prop, 64 bf16 feats, 2 edges/wave (32 lanes x uint each) --------

__global__ __launch_bounds__(256) void prop64p_k(const uint* __restrict__ X,  // bf16x2
                                                 float2* __restrict__ Y,      // fp32 out
                                                 const int* __restrict__ off,
                                                 const int2* __restrict__ cc,
                                                 const float* __restrict__ dinv) {
  int node = blockIdx.x * 4 + (threadIdx.x >> 6);
  if (node >= N_NODES) return;
  uint lane = threadIdx.x & 63u;
  uint sub = lane >> 5, o32 = lane & 31u;
  float di = dinv[node];
  uint s = X[(uint)node * 32u + o32];
  float2 acc = make_float2(0.f, 0.f);
  int e = off[node], e1 = off[node + 1];
  for (; e + 7 < e1; e += 8) {
    int2 q[4];
    uint v[4];
#pragma unroll
    for (int j = 0; j < 4; j++) q[j] = cc[e + 2 * j + sub];
#pragma unroll
    for (int j = 0; j < 4; j++) v[j] = X[(uint)q[j].x * 32u + o32];
#pragma unroll
    for (int j = 0; j < 4; j++) {
      float w = __int_as_float(q[j].y);
      acc.x = fmaf(bflo(v[j]), w, acc.x);
      acc.y = fmaf(bfhi(v[j]), w, acc.y);
    }
  }
  for (; e + 1 < e1; e += 2) {
    int2 q = cc[e + sub];
    uint v = X[(uint)q.x * 32u + o32];
    float w = __int_as_float(q.y);
    acc.x = fmaf(bflo(v), w, acc.x);
    acc.y = fmaf(bfhi(v), w, acc.y);
  }
  if (e < e1 && sub == 0) {
    int2 q = cc[e];
    uint v = X[(uint)q.x * 32u + o32];
    float w = __int_as_float(q.y);
    acc.x = fmaf(bflo(v), w, acc.x);
    acc.y = fmaf(bfhi(v), w, acc.y);
  }
  acc.x += __shfl_xor(acc.x, 32);
  acc.y += __shfl_xor(acc.y, 32);
  float sc = di * di;
  acc.x = fmaf(bflo(s), sc, acc.x);
  acc.y = fmaf(bfhi(s), sc, acc.y);
  if (sub == 0) Y[(uint)node * 32u + o32] = acc;
}

// ---------------- fp32-math GEMM, K=128; A fp32 or bf16; C fp32 or bf16 ----------

template <int FOUT, bool RELU, bool BF16OUT, bool ABF16>
__global__ __launch_bounds__(256) void gemm_k128(const void* __restrict__ Av,
                                                 const float* __restrict__ W,
                                                 void* __restrict__ Cv) {
  __shared__ float Al[64 * 128];      // 32 KB
  constexpr int TC = FOUT / 4;        // 32 or 16
  constexpr int R = 64 / (256 / TC);  // 8 or 4
  int tid = threadIdx.x;
  int row0 = blockIdx.x * 64;
  if (ABF16) {
    const uint2* Ab = (const uint2*)Av;  // 4 bf16 per uint2
    for (int i = tid; i < 64 * 32; i += 256) {
      int r = i >> 5, c = i & 31;
      int gr = row0 + r;
      float4 f = make_float4(0.f, 0.f, 0.f, 0.f);
      if (gr < N_NODES) {
        uint2 u = Ab[(uint)gr * 32u + c];
        f.x = bflo(u.x);
        f.y = bfhi(u.x);
        f.z = bflo(u.y);
        f.w = bfhi(u.y);
      }
      ((float4*)Al)[i] = f;
    }
  } else {
    const float4* Af = (const float4*)Av;
    for (int i = tid; i < 64 * 32; i += 256) {
      int r = i >> 5;
      int gr = row0 + r;
      float4 v = make_float4(0.f, 0.f, 0.f, 0.f);
      if (gr < N_NODES) v = Af[(uint)gr * 32u + (i & 31)];
      ((float4*)Al)[i] = v;
    }
  }
  __syncthreads();
  int tc = tid % TC, tr = tid / TC;
  int c0 = tc * 4, r0 = tr * R;
  float acc[R][4];
#pragma unroll
  for (int r = 0; r < R; r++)
#pragma unroll
    for (int c = 0; c < 4; c++) acc[r][c] = 0.f;

  for (int k = 0; k < 128; k += 4) {
    float4 w[4];
#pragma unroll
    for (int kk = 0; kk < 4; kk++) w[kk] = *(const float4*)&W[(k + kk) * FOUT + c0];
    float4 a[R];
#pragma unroll
    for (int r = 0; r < R; r++) a[r] = *(const float4*)&Al[(r0 + r) * 128 + k];
#pragma unroll
    for (int kk = 0; kk < 4; kk++) {
#pragma unroll
      for (int r = 0; r < R; r++) {
        float av = (kk == 0) ? a[r].x : (kk == 1) ? a[r].y : (kk == 2) ? a[r].z : a[r].w;
        acc[r][0] = fmaf(av, w[kk].x, acc[r][0]);
        acc[r][1] = fmaf(av, w[kk].y, acc[r][1]);
        acc[r][2] = fmaf(av, w[kk].z, acc[r][2]);
        acc[r][3] = fmaf(av, w[kk].w, acc[r][3]);
      }
    }
  }
#pragma unroll
  for (int r = 0; r < R; r++) {
    int gr = row0 + r0 + r;
    if (gr < N_NODES) {
      float x0v = acc[r][0], x1v = acc[r][1], x2v = acc[r][2], x3v = acc[r][3];
      if (RELU) {
        x0v = fmaxf(x0v, 0.f); x1v = fmaxf(x1v, 0.f);
        x2v = fmaxf(x2v, 0.f); x3v = fmaxf(x3v, 0.f);
      }
      if (BF16OUT) {
        uint2 p;
        p.x = bfpack(x0v, x1v);
        p.y = bfpack(x2v, x3v);
        ((uint2*)Cv)[(uint)gr * (FOUT / 4) + tc] = p;
      } else {
        float4 v;
        v.x = x0v; v.y = x1v; v.z = x2v; v.w = x3v;
        ((float4*)Cv)[(uint)gr * (FOUT / 4) + tc] = v;
      }
    }
  }
}

// ---------------- launch ----------------
// Pipeline (uses (PX)W == P(XW)):
//   W01 = W0@W1
//   x0b = bf16(feat @ W01)
//   x1b = bf16(relu(P x0b))
//   t2b = bf16(x1b @ W2)       (aliases x0b)
//   out = P t2b                (fp32 out)

extern "C" void kernel_launch(void* const* d_in, const int* in_sizes, int n_in,
                              void* d_out, int out_size, void* d_ws, size_t ws_size,
                              hipStream_t stream) {
  const float* feat = (const float*)d_in[0];
  const int* ei = (const int*)d_in[1];  // int32 per harness contract
  const float* W0 = (const float*)d_in[2];
  const float* W1 = (const float*)d_in[3];
  const float* W2 = (const float*)d_in[4];
  float2* out = (float2*)d_out;

  char* ws = (char*)d_ws;
  uint* x0b = (uint*)ws;       ws += (size_t)N_NODES * 128 * 2;   // bf16, 25.6 MB
  uint* x1b = (uint*)ws;       ws += (size_t)N_NODES * 128 * 2;   // bf16; binbuf aliases
  int2* cc = (int2*)ws;        ws += (size_t)N_EDGES * 8;
  float* dinv = (float*)ws;    ws += (size_t)N_NODES * 4;
  int* off = (int*)ws;         ws += (size_t)(N_NODES + 2) * 4;
  int* hist = (int*)ws;        ws += (size_t)NBLK * NB * 4;
  int* pos = (int*)ws;         ws += (size_t)NBLK * NB * 4;
  int* coltot = (int*)ws;      ws += (size_t)NB * 4;
  int* base = (int*)ws;        ws += (size_t)NB * 4;
  float* W01 = (float*)ws;     ws += 128 * 128 * 4;
  unsigned* binbuf = (unsigned*)x1b;  // 6.4 MB, dead before x1b written
  uint* t2b = x0b;                    // bf16 N x 64, x0b dead after prop128p

  hist_k<<<NBLK, 256, 0, stream>>>(ei, hist);
  scan_hist_k<<<NB, 64, 0, stream>>>(hist, pos, coltot);
  base_scan_k<<<1, 512, 0, stream>>>(coltot, base);
  bin_k<<<NBLK, 256, 0, stream>>>(ei, pos, base, binbuf);
  bucket_off_k<<<NB, 256, 0, stream>>>(binbuf, base, coltot, off, dinv);
  csr_k<<<NB, 256, 0, stream>>>(binbuf, off, dinv, cc);

  w01_k<<<64, 256, 0, stream>>>(W0, W1, W01);
  gemm_k128<128, false, true, false><<<(N_NODES + 63) / 64, 256, 0, stream>>>(feat, W01, x0b);
  prop128p_k<true><<<(N_NODES + 3) / 4, 256, 0, stream>>>((const uint2*)x0b, (uint2*)x1b, off, cc, dinv);
  gemm_k128<64, false, true, true><<<(N_NODES + 63) / 64, 256, 0, stream>>>(x1b, W2, t2b);
  prop64p_k<<<(N_NODES + 3) / 4, 256, 0, stream>>>(t2b, out, off, cc, dinv);
}

// Round 8
// 215.874 us; speedup vs baseline: 3.3722x; 1.2362x over previous
//
#include <hip/hip_runtime.h>

#define N_NODES 100000
#define N_EDGES 1600000
#define NB 391            // ceil(N_NODES/256) row-buckets of 256 rows
#define NBLK 256          // blocks for binning passes
#define CHUNK 6250        // ceil(N_EDGES/NBLK)

typedef unsigned int uint;
typedef __attribute__((ext_vector_type(8))) short short8v;  // 8 bf16 (4 VGPRs)
typedef __attribute__((ext_vector_type(4))) float f32x4;

// ---------------- bf16 helpers ----------------

__device__ __forceinline__ uint bfrn(float x) {  // fp32 -> bf16 bits (RN)
  uint u = __float_as_uint(x);
  u += 0x7fffu + ((u >> 16) & 1u);
  return u >> 16;
}
__device__ __forceinline__ uint bfpack(float a, float b) {
  return bfrn(a) | (bfrn(b) << 16);
}
__device__ __forceinline__ float bflo(uint u) { return __uint_as_float(u << 16); }
__device__ __forceinline__ float bfhi(uint u) { return __uint_as_float(u & 0xffff0000u); }

// ---------------- pass 1: per-block bucket histogram (LDS only) ----------------

__global__ __launch_bounds__(256) void hist_k(const int* __restrict__ ei,
                                              int* __restrict__ hist) {
  __shared__ int lh[NB];
  for (int i = threadIdx.x; i < NB; i += 256) lh[i] = 0;
  __syncthreads();
  int b = blockIdx.x;
  int e1 = min(b * CHUNK + CHUNK, N_EDGES);
  for (int e = b * CHUNK + threadIdx.x; e < e1; e += 256) {
    atomicAdd(&lh[ei[e] >> 8], 1);
  }
  __syncthreads();
  for (int i = threadIdx.x; i < NB; i += 256) hist[b * NB + i] = lh[i];
}

// ---------------- pass 2: per-bucket column scan + bucket totals ----------------

__global__ __launch_bounds__(64) void scan_hist_k(const int* __restrict__ hist,
                                                  int* __restrict__ pos,
                                                  int* __restrict__ coltot) {
  int k = blockIdx.x, lane = threadIdx.x;
  int carry = 0;
  for (int c = 0; c < 4; c++) {
    int b = c * 64 + lane;
    int v = hist[b * NB + k];
    int x = v;
    for (int d = 1; d < 64; d <<= 1) {
      int t = __shfl_up(x, d);
      if (lane >= d) x += t;
    }
    pos[b * NB + k] = carry + x - v;  // exclusive within bucket
    carry += __shfl(x, 63);
  }
  if (lane == 0) coltot[k] = carry;
}

// ---------------- pass 2b: exclusive scan of bucket totals ----------------

__global__ __launch_bounds__(512) void base_scan_k(const int* __restrict__ coltot,
                                                   int* __restrict__ base) {
  __shared__ int s[512];
  int v = (threadIdx.x < NB) ? coltot[threadIdx.x] : 0;
  s[threadIdx.x] = v;
  __syncthreads();
  for (int d = 1; d < 512; d <<= 1) {
    int t = (threadIdx.x >= d) ? s[threadIdx.x - d] : 0;
    __syncthreads();
    s[threadIdx.x] += t;
    __syncthreads();
  }
  if (threadIdx.x < NB) base[threadIdx.x] = s[threadIdx.x] - v;  // exclusive
}

// ---------------- pass 3: stable binned scatter ----------------

__global__ __launch_bounds__(256) void bin_k(const int* __restrict__ ei,
                                             const int* __restrict__ pos,
                                             const int* __restrict__ base,
                                             unsigned* __restrict__ binbuf) {
  __shared__ int lcur[NB];
  int b = blockIdx.x;
  for (int i = threadIdx.x; i < NB; i += 256) lcur[i] = pos[b * NB + i] + base[i];
  __syncthreads();
  int e1 = min(b * CHUNK + CHUNK, N_EDGES);
  for (int e = b * CHUNK + threadIdx.x; e < e1; e += 256) {
    int r = ei[e];
    int c = ei[N_EDGES + e];
    int p = atomicAdd(&lcur[r >> 8], 1);
    binbuf[p] = ((unsigned)(r & 255) << 24) | (unsigned)c;  // c < 2^17 fits
  }
}

// ---------------- pass 4: per-bucket LDS histogram -> deg/off/dinv ----------------

__global__ __launch_bounds__(256) void bucket_off_k(const unsigned* __restrict__ binbuf,
                                                    const int* __restrict__ base,
                                                    const int* __restrict__ coltot,
                                                    int* __restrict__ off,
                                                    float* __restrict__ dinv) {
  __shared__ int cnt[256];
  __shared__ int sc[256];
  int k = blockIdx.x, row0 = k << 8;
  cnt[threadIdx.x] = 0;
  __syncthreads();
  int e0 = base[k], e1 = e0 + coltot[k];
  for (int e = e0 + threadIdx.x; e < e1; e += 256) atomicAdd(&cnt[binbuf[e] >> 24], 1);
  __syncthreads();
  int v = cnt[threadIdx.x];
  sc[threadIdx.x] = v;
  __syncthreads();
  for (int d = 1; d < 256; d <<= 1) {
    int t = (threadIdx.x >= d) ? sc[threadIdx.x - d] : 0;
    __syncthreads();
    sc[threadIdx.x] += t;
    __syncthreads();
  }
  int row = row0 + threadIdx.x;
  if (row < N_NODES) {
    off[row] = e0 + sc[threadIdx.x] - v;  // exclusive prefix
    dinv[row] = rsqrtf((float)v + 1.0f);  // +1 = self-loop
  }
  if (k == NB - 1 && threadIdx.x == 0) off[N_NODES] = N_EDGES;
}

// ---------------- pass 5: within-bucket placement + coef fuse ----------------

__global__ __launch_bounds__(256) void csr_k(const unsigned* __restrict__ binbuf,
                                             const int* __restrict__ off,
                                             const float* __restrict__ dinv,
                                             int2* __restrict__ cc) {
  __shared__ int cur[256];
  int b = blockIdx.x, row0 = b << 8;
  int nrows = min(256, N_NODES - row0);
  if (threadIdx.x < nrows) cur[threadIdx.x] = off[row0 + threadIdx.x];
  __syncthreads();
  int e0 = off[row0];
  int e1 = off[min(row0 + 256, N_NODES)];
  for (int e = e0 + threadIdx.x; e < e1; e += 256) {
    unsigned u = binbuf[e];
    int rl = u >> 24;
    int c = (int)(u & 0xFFFFFFu);
    int slot = atomicAdd(&cur[rl], 1);
    float w = dinv[row0 + rl] * dinv[c];
    cc[slot] = make_int2(c, __float_as_int(w));
  }
}

// ---------------- W01 = W0 @ W1, packed bf16 MFMA-B-fragment layout --------------
// Packed index for element (k, f), NCT = FOUT/16:
//   ks=k>>5, j=k&7, lq=(k>>3)&3, lane=(lq<<4)|(f&15), ct=f>>4
//   idx = ((ks*NCT + ct)*64 + lane)*8 + j

__global__ __launch_bounds__(256) void w01p_k(const float* __restrict__ W0,
                                              const float* __restrict__ W1,
                                              unsigned short* __restrict__ W01p) {
  int g = blockIdx.x * 256 + threadIdx.x;  // 16384
  int k = g >> 7, f = g & 127;
  float s = 0.f;
  for (int kk = 0; kk < 128; kk++) s = fmaf(W0[k * 128 + kk], W1[kk * 128 + f], s);
  int ks = k >> 5, j = k & 7, lq = (k >> 3) & 3;
  int lane = (lq << 4) | (f & 15), ct = f >> 4;
  W01p[((ks * 8 + ct) * 64 + lane) * 8 + j] = (unsigned short)bfrn(s);
}

__global__ __launch_bounds__(256) void w2p_k(const float* __restrict__ W2,
                                             unsigned short* __restrict__ W2p) {
  int g = blockIdx.x * 256 + threadIdx.x;  // 8192
  int k = g >> 6, f = g & 63;
  int ks = k >> 5, j = k & 7, lq = (k >> 3) & 3;
  int lane = (lq << 4) | (f & 15), ct = f >> 4;
  W2p[((ks * 4 + ct) * 64 + lane) * 8 + j] = (unsigned short)bfrn(W2[k * 64 + f]);
}

// ---------------- MFMA GEMM: C[64rows x FOUT] = A[64 x 128] @ W[128 x FOUT] ------
// 4 waves, wave w owns rows w*16..w*16+15, all FOUT cols (NCT 16-col tiles).
// A staged in LDS bf16 with XOR swizzle byte^=(row&7)<<4 (256B rows -> bank spread).
// W pre-packed so each B-fragment is one contiguous 16B/lane ds_read.

template <int FOUT, bool ABF16>
__global__ __launch_bounds__(256) void mgemm_k(const void* __restrict__ Av,
                                               const unsigned short* __restrict__ Wp,
                                               unsigned short* __restrict__ Cb) {
  constexpr int NCT = FOUT / 16;
  __shared__ uint4 Al4[64 * 16];          // 16 KB: 64 rows x 128 bf16 (swizzled)
  __shared__ uint4 Wl4[FOUT * 16];        // 32/16 KB packed fragments
  char* Al = (char*)Al4;
  int tid = threadIdx.x;
  int row0 = blockIdx.x * 64;
  for (int i = tid; i < FOUT * 16; i += 256) Wl4[i] = ((const uint4*)Wp)[i];
  if (ABF16) {
    const uint4* Ab = (const uint4*)Av;
    for (int i = tid; i < 64 * 16; i += 256) {
      int r = i >> 4, c8 = i & 15;  // c8: 8-elem chunk
      int gr = row0 + r;
      uint4 v = make_uint4(0, 0, 0, 0);
      if (gr < N_NODES) v = Ab[(uint)gr * 16u + c8];
      int byte = (r * 256 + c8 * 16) ^ ((r & 7) << 4);
      *(uint4*)(Al + byte) = v;
    }
  } else {
    const float4* Af = (const float4*)Av;
    for (int i = tid; i < 64 * 32; i += 256) {
      int r = i >> 5, c4 = i & 31;  // c4: 4-elem chunk
      int gr = row0 + r;
      float4 v = make_float4(0.f, 0.f, 0.f, 0.f);
      if (gr < N_NODES) v = Af[(uint)gr * 32u + c4];
      uint2 p;
      p.x = bfpack(v.x, v.y);
      p.y = bfpack(v.z, v.w);
      int byte = (r * 256 + c4 * 8) ^ ((r & 7) << 4);
      *(uint2*)(Al + byte) = p;
    }
  }
  __syncthreads();
  int lane = tid & 63, w = tid >> 6;
  f32x4 acc[NCT];
#pragma unroll
  for (int ct = 0; ct < NCT; ct++) acc[ct] = (f32x4){0.f, 0.f, 0.f, 0.f};
  int arow = w * 16 + (lane & 15);
#pragma unroll
  for (int ks = 0; ks < 4; ks++) {
    int abyte = (arow * 256 + ks * 64 + (lane >> 4) * 16) ^ ((arow & 7) << 4);
    short8v a = *(const short8v*)(Al + abyte);
#pragma unroll
    for (int ct = 0; ct < NCT; ct++) {
      short8v b = *(const short8v*)((const char*)Wl4 + ((ks * NCT + ct) * 64 + lane) * 16);
      acc[ct] = __builtin_amdgcn_mfma_f32_16x16x32_bf16(a, b, acc[ct], 0, 0, 0);
    }
  }
  // epilogue: D col = lane&15, row = (lane>>4)*4 + j
#pragma unroll
  for (int ct = 0; ct < NCT; ct++) {
#pragma unroll
    for (int j = 0; j < 4; j++) {
      int row = row0 + w * 16 + ((lane >> 4) << 2) + j;
      int col = ct * 16 + (lane & 15);
      if (row < N_NODES) Cb[(uint)row * FOUT + col] = (unsigned short)bfrn(acc[ct][j]);
    }
  }
}

// ---------------- prop, 128 bf16 feats, 2 edges/wave (32 lanes x uint2 each) ------

template <bool RELU>
__global__ __launch_bounds__(256) void prop128p_k(const uint2* __restrict__ X,  // bf16x4
                                                  uint2* __restrict__ Yb,       // bf16x4
                                                  const int* __restrict__ off,
                                                  const int2* __restrict__ cc,
                                                  const float* __restrict__ dinv) {
  int node = blockIdx.x * 4 + (threadIdx.x >> 6);
  if (node >= N_NODES) return;
  uint lane = threadIdx.x & 63u;
  uint sub = lane >> 5, o32 = lane & 31u;
  float di = dinv[node];
  float sc = di * di;
  uint2 s = X[(uint)node * 32u + o32];
  float4 acc = make_float4(0.f, 0.f, 0.f, 0.f);
  int e = off[node], e1 = off[node + 1];
  for (; e + 7 < e1; e += 8) {  // 4 pairs = 8 edges
    int2 q[4];
    uint2 v[4];
#pragma unroll
    for (int j = 0; j < 4; j++) q[j] = cc[e + 2 * j + sub];
#pragma unroll
    for (int j = 0; j < 4; j++) v[j] = X[(uint)q[j].x * 32u + o32];
#pragma unroll
    for (int j = 0; j < 4; j++) {
      float w = __int_as_float(q[j].y);
      acc.x = fmaf(bflo(v[j].x), w, acc.x);
      acc.y = fmaf(bfhi(v[j].x), w, acc.y);
      acc.z = fmaf(bflo(v[j].y), w, acc.z);
      acc.w = fmaf(bfhi(v[j].y), w, acc.w);
    }
  }
  for (; e + 1 < e1; e += 2) {  // remaining pairs
    int2 q = cc[e + sub];
    uint2 v = X[(uint)q.x * 32u + o32];
    float w = __int_as_float(q.y);
    acc.x = fmaf(bflo(v.x), w, acc.x);
    acc.y = fmaf(bfhi(v.x), w, acc.y);
    acc.z = fmaf(bflo(v.y), w, acc.z);
    acc.w = fmaf(bfhi(v.y), w, acc.w);
  }
  if (e < e1 && sub == 0) {  // single tail edge: half-wave only
    int2 q = cc[e];
    uint2 v = X[(uint)q.x * 32u + o32];
    float w = __int_as_float(q.y);
    acc.x = fmaf(bflo(v.x), w, acc.x);
    acc.y = fmaf(bfhi(v.x), w, acc.y);
    acc.z = fmaf(bflo(v.y), w, acc.z);
    acc.w = fmaf(bfhi(v.y), w, acc.w);
  }
  acc.x += __shfl_xor(acc.x, 32);
  acc.y += __shfl_xor(acc.y, 32);
  acc.z += __shfl_xor(acc.z, 32);
  acc.w += __shfl_xor(acc.w, 32);
  acc.x = fmaf(bflo(s.x), sc, acc.x);
  acc.y = fmaf(bfhi(s.x), sc, acc.y);
  acc.z = fmaf(bflo(s.y), sc, acc.z);
  acc.w = fmaf(bfhi(s.y), sc, acc.w);
  if (RELU) {
    acc.x = fmaxf(acc.x, 0.f); acc.y = fmaxf(acc.y, 0.f);
    acc.z = fmaxf(acc.z, 0.f); acc.w = fmaxf(acc.w, 0.f);
  }
  if (sub == 0) {
    uint2 p;
    p.x = bfpack(acc.x, acc.y);
    p.y = bfpack(acc.z, acc.w);
    Yb[(uint)node * 32u + o32] = p;
  }
}

// ---------------- prop, 64 bf16 feats, 2 edges/wave (32 lanes x uint each) --------

__global__ __launch_bounds__(256) void prop64p_k(const uint* __restrict__ X,  // bf16x2
                                                 float2* __restrict__ Y,      // fp32 out
                                                 const int* __restrict__ off,
                                                 const int2* __restrict__ cc,
                                                 const float* __restrict__ dinv) {
  int node = blockIdx.x * 4 + (threadIdx.x >> 6);
  if (node >= N_NODES) return;
  uint lane = threadIdx.x & 63u;
  uint sub = lane >> 5, o32 = lane & 31u;
  float di = dinv[node];
  uint s = X[(uint)node * 32u + o32];
  float2 acc = make_float2(0.f, 0.f);
  int e = off[node], e1 = off[node + 1];
  for (; e + 7 < e1; e += 8) {
    int2 q[4];
    uint v[4];
#pragma unroll
    for (int j = 0; j < 4; j++) q[j] = cc[e + 2 * j + sub];
#pragma unroll
    for (int j = 0; j < 4; j++) v[j] = X[(uint)q[j].x * 32u + o32];
#pragma unroll
    for (int j = 0; j < 4; j++) {
      float w = __int_as_float(q[j].y);
      acc.x = fmaf(bflo(v[j]), w, acc.x);
      acc.y = fmaf(bfhi(v[j]), w, acc.y);
    }
  }
  for (; e + 1 < e1; e += 2) {
    int2 q = cc[e + sub];
    uint v = X[(uint)q.x * 32u + o32];
    float w = __int_as_float(q.y);
    acc.x = fmaf(bflo(v), w, acc.x);
    acc.y = fmaf(bfhi(v), w, acc.y);
  }
  if (e < e1 && sub == 0) {
    int2 q = cc[e];
    uint v = X[(uint)q.x * 32u + o32];
    float w = __int_as_float(q.y);
    acc.x = fmaf(bflo(v), w, acc.x);
    acc.y = fmaf(bfhi(v), w, acc.y);
  }
  acc.x += __shfl_xor(acc.x, 32);
  acc.y += __shfl_xor(acc.y, 32);
  float sc = di * di;
  acc.x = fmaf(bflo(s), sc, acc.x);
  acc.y = fmaf(bfhi(s), sc, acc.y);
  if (sub == 0) Y[(uint)node * 32u + o32] = acc;
}

// ---------------- launch ----------------
// Pipeline (uses (PX)W == P(XW)):
//   W01p = pack(bf16(W0@W1)); W2p = pack(bf16(W2))
//   x0b = bf16(feat @ W01)     [MFMA]
//   x1b = bf16(relu(P x0b))
//   t2b = bf16(x1b @ W2)       [MFMA, aliases x0b]
//   out = P t2b                (fp32 out)

extern "C" void kernel_launch(void* const* d_in, const int* in_sizes, int n_in,
                              void* d_out, int out_size, void* d_ws, size_t ws_size,
                              hipStream_t stream) {
  const float* feat = (const float*)d_in[0];
  const int* ei = (const int*)d_in[1];  // int32 per harness contract
  const float* W0 = (const float*)d_in[2];
  const float* W1 = (const float*)d_in[3];
  const float* W2 = (const float*)d_in[4];
  float2* out = (float2*)d_out;

  char* ws = (char*)d_ws;
  uint* x0b = (uint*)ws;       ws += (size_t)N_NODES * 128 * 2;   // bf16, 25.6 MB
  uint* x1b = (uint*)ws;       ws += (size_t)N_NODES * 128 * 2;   // bf16; binbuf aliases
  int2* cc = (int2*)ws;        ws += (size_t)N_EDGES * 8;
  float* dinv = (float*)ws;    ws += (size_t)N_NODES * 4;
  int* off = (int*)ws;         ws += (size_t)(N_NODES + 2) * 4;
  int* hist = (int*)ws;        ws += (size_t)NBLK * NB * 4;
  int* pos = (int*)ws;         ws += (size_t)NBLK * NB * 4;
  int* coltot = (int*)ws;      ws += (size_t)NB * 4;
  int* base = (int*)ws;        ws += (size_t)NB * 4;
  unsigned short* W01p = (unsigned short*)ws; ws += 128 * 128 * 2;
  unsigned short* W2p = (unsigned short*)ws;  ws += 128 * 64 * 2;
  unsigned* binbuf = (unsigned*)x1b;  // 6.4 MB, dead before x1b written
  unsigned short* t2b = (unsigned short*)x0b;  // bf16 N x 64, x0b dead after prop128p

  hist_k<<<NBLK, 256, 0, stream>>>(ei, hist);
  scan_hist_k<<<NB, 64, 0, stream>>>(hist, pos, coltot);
  base_scan_k<<<1, 512, 0, stream>>>(coltot, base);
  bin_k<<<NBLK, 256, 0, stream>>>(ei, pos, base, binbuf);
  bucket_off_k<<<NB, 256, 0, stream>>>(binbuf, base, coltot, off, dinv);
  csr_k<<<NB, 256, 0, stream>>>(binbuf, off, dinv, cc);

  w01p_k<<<64, 256, 0, stream>>>(W0, W1, W01p);
  w2p_k<<<32, 256, 0, stream>>>(W2, W2p);
  mgemm_k<128, false><<<(N_NODES + 63) / 64, 256, 0, stream>>>(feat, W01p, (unsigned short*)x0b);
  prop128p_k<true><<<(N_NODES + 3) / 4, 256, 0, stream>>>((const uint2*)x0b, (uint2*)x1b, off, cc, dinv);
  mgemm_k<64, true><<<(N_NODES + 63) / 64, 256, 0, stream>>>(x1b, W2p, t2b);
  prop64p_k<<<(N_NODES + 3) / 4, 256, 0, stream>>>((const uint*)t2b, out, off, cc, dinv);
}

// Round 9
// 198.359 us; speedup vs baseline: 3.6700x; 1.0883x over previous
//
#include <hip/hip_runtime.h>

#define N_NODES 100000
#define N_EDGES 1600000
#define NB 391            // ceil(N_NODES/256) row-buckets of 256 rows
#define NBLK 256          // blocks for binning pass
#define CHUNK 6250        // ceil(N_EDGES/NBLK)
#define CAP 5120          // per-bucket binbuf capacity (mean 4096, sigma 64)

typedef unsigned int uint;
typedef __attribute__((ext_vector_type(8))) short short8v;  // 8 bf16 (4 VGPRs)
typedef __attribute__((ext_vector_type(4))) float f32x4;

// ---------------- bf16 helpers ----------------

__device__ __forceinline__ uint bfrn(float x) {  // fp32 -> bf16 bits (RN)
  uint u = __float_as_uint(x);
  u += 0x7fffu + ((u >> 16) & 1u);
  return u >> 16;
}
__device__ __forceinline__ uint bfpack(float a, float b) {
  return bfrn(a) | (bfrn(b) << 16);
}
__device__ __forceinline__ float bflo(uint u) { return __uint_as_float(u << 16); }
__device__ __forceinline__ float bfhi(uint u) { return __uint_as_float(u & 0xffff0000u); }

// ---------------- build pass 1: hist + reserve + scatter (one kernel) ----------------
// gcur[k] pre-initialized to k*CAP; blocks reserve ranges with one global atomic
// per (block,bucket), then scatter their chunk stably into the reserved runs.

__global__ __launch_bounds__(256) void binfused_k(const int* __restrict__ ei,
                                                  int* __restrict__ gcur,
                                                  unsigned* __restrict__ binbuf) {
  __shared__ int lh[NB];
  for (int i = threadIdx.x; i < NB; i += 256) lh[i] = 0;
  __syncthreads();
  int b = blockIdx.x;
  int ebeg = b * CHUNK, e1 = min(ebeg + CHUNK, N_EDGES);
  for (int e = ebeg + threadIdx.x; e < e1; e += 256) {
    atomicAdd(&lh[ei[e] >> 8], 1);
  }
  __syncthreads();
  for (int i = threadIdx.x; i < NB; i += 256) {
    int c = lh[i];
    lh[i] = c ? atomicAdd(&gcur[i], c) : 0;  // lh becomes this block's run cursor
  }
  __syncthreads();
  for (int e = ebeg + threadIdx.x; e < e1; e += 256) {
    int r = ei[e];
    int c = ei[N_EDGES + e];
    int p = atomicAdd(&lh[r >> 8], 1);
    binbuf[p] = ((unsigned)(r & 255) << 24) | (unsigned)c;  // c < 2^17 fits
  }
}

// ---------------- build pass 2: per-bucket count/scan -> off,dinv; place cc ----------

__global__ __launch_bounds__(256) void buckoff_k(const unsigned* __restrict__ binbuf,
                                                 const int* __restrict__ gcur,
                                                 int* __restrict__ off,
                                                 float* __restrict__ dinv,
                                                 uint* __restrict__ cc) {
  __shared__ int cnt[256];
  __shared__ int sc[256];
  __shared__ int sbase;
  int k = blockIdx.x, row0 = k << 8;
  int tid = threadIdx.x;
  if (tid < 64) {  // base_k = sum_{j<k} (gcur[j] - j*CAP)
    int s = 0;
    for (int j = tid; j < k; j += 64) s += gcur[j] - j * CAP;
#pragma unroll
    for (int d = 32; d; d >>= 1) s += __shfl_xor(s, d);
    if (tid == 0) sbase = s;
  }
  cnt[tid] = 0;
  __syncthreads();
  int n = gcur[k] - k * CAP;  // this bucket's edge count
  int sb = k * CAP;
  for (int t = tid; t < n; t += 256) atomicAdd(&cnt[binbuf[sb + t] >> 24], 1);
  __syncthreads();
  int v = cnt[tid];
  sc[tid] = v;
  __syncthreads();
  for (int d = 1; d < 256; d <<= 1) {
    int t = (tid >= d) ? sc[tid - d] : 0;
    __syncthreads();
    sc[tid] += t;
    __syncthreads();
  }
  int e0 = sbase;
  int row = row0 + tid;
  int mystart = e0 + sc[tid] - v;
  if (row < N_NODES) {
    off[row] = mystart;
    dinv[row] = rsqrtf((float)v + 1.0f);  // +1 = self-loop
  }
  if (k == NB - 1 && tid == 0) off[N_NODES] = N_EDGES;
  __syncthreads();
  cnt[tid] = mystart;  // reuse as placement cursor
  __syncthreads();
  for (int t = tid; t < n; t += 256) {
    unsigned u = binbuf[sb + t];
    int slot = atomicAdd(&cnt[u >> 24], 1);
    cc[slot] = u & 0xFFFFFFu;
  }
}

// ---------------- weight pack (W01=W0@W1, W2) + gcur init, one kernel -------------
// Packed B-fragment index for element (k,f), NCT=FOUT/16:
//   ks=k>>5, j=k&7, lq=(k>>3)&3, lane=(lq<<4)|(f&15), ct=f>>4
//   idx = ((ks*NCT + ct)*64 + lane)*8 + j

__global__ __launch_bounds__(256) void wpack_k(const float* __restrict__ W0,
                                               const float* __restrict__ W1,
                                               const float* __restrict__ W2,
                                               unsigned short* __restrict__ W01p,
                                               unsigned short* __restrict__ W2p,
                                               int* __restrict__ gcur) {
  int b = blockIdx.x;
  if (b < 64) {
    int g = b * 256 + threadIdx.x;  // 16384
    int k = g >> 7, f = g & 127;
    float s = 0.f;
    for (int kk = 0; kk < 128; kk++) s = fmaf(W0[k * 128 + kk], W1[kk * 128 + f], s);
    int ks = k >> 5, j = k & 7, lq = (k >> 3) & 3;
    int lane = (lq << 4) | (f & 15), ct = f >> 4;
    W01p[((ks * 8 + ct) * 64 + lane) * 8 + j] = (unsigned short)bfrn(s);
  } else if (b < 96) {
    int g = (b - 64) * 256 + threadIdx.x;  // 8192
    int k = g >> 6, f = g & 63;
    int ks = k >> 5, j = k & 7, lq = (k >> 3) & 3;
    int lane = (lq << 4) | (f & 15), ct = f >> 4;
    W2p[((ks * 4 + ct) * 64 + lane) * 8 + j] = (unsigned short)bfrn(W2[k * 64 + f]);
  } else {
    for (int i = threadIdx.x; i < NB; i += 256) gcur[i] = i * CAP;
  }
}

// ---------------- MFMA GEMM: C[64 x FOUT] = A[64 x 128] @ W[128 x FOUT] -----------
// Epilogue scales row r by dinv[r] (pre-scaling for the coefficient-free prop).

template <int FOUT, bool ABF16>
__global__ __launch_bounds__(256) void mgemm_k(const void* __restrict__ Av,
                                               const unsigned short* __restrict__ Wp,
                                               unsigned short* __restrict__ Cb,
                                               const float* __restrict__ dinv) {
  constexpr int NCT = FOUT / 16;
  __shared__ uint4 Al4[64 * 16];    // 16 KB: 64 rows x 128 bf16 (swizzled)
  __shared__ uint4 Wl4[FOUT * 16];  // packed fragments
  char* Al = (char*)Al4;
  int tid = threadIdx.x;
  int row0 = blockIdx.x * 64;
  for (int i = tid; i < FOUT * 16; i += 256) Wl4[i] = ((const uint4*)Wp)[i];
  if (ABF16) {
    const uint4* Ab = (const uint4*)Av;
    for (int i = tid; i < 64 * 16; i += 256) {
      int r = i >> 4, c8 = i & 15;
      int gr = row0 + r;
      uint4 v = make_uint4(0, 0, 0, 0);
      if (gr < N_NODES) v = Ab[(uint)gr * 16u + c8];
      int byte = (r * 256 + c8 * 16) ^ ((r & 7) << 4);
      *(uint4*)(Al + byte) = v;
    }
  } else {
    const float4* Af = (const float4*)Av;
    for (int i = tid; i < 64 * 32; i += 256) {
      int r = i >> 5, c4 = i & 31;
      int gr = row0 + r;
      float4 v = make_float4(0.f, 0.f, 0.f, 0.f);
      if (gr < N_NODES) v = Af[(uint)gr * 32u + c4];
      uint2 p;
      p.x = bfpack(v.x, v.y);
      p.y = bfpack(v.z, v.w);
      int byte = (r * 256 + c4 * 8) ^ ((r & 7) << 4);
      *(uint2*)(Al + byte) = p;
    }
  }
  __syncthreads();
  int lane = tid & 63, w = tid >> 6;
  f32x4 acc[NCT];
#pragma unroll
  for (int ct = 0; ct < NCT; ct++) acc[ct] = (f32x4){0.f, 0.f, 0.f, 0.f};
  int arow = w * 16 + (lane & 15);
#pragma unroll
  for (int ks = 0; ks < 4; ks++) {
    int abyte = (arow * 256 + ks * 64 + (lane >> 4) * 16) ^ ((arow & 7) << 4);
    short8v a = *(const short8v*)(Al + abyte);
#pragma unroll
    for (int ct = 0; ct < NCT; ct++) {
      short8v b = *(const short8v*)((const char*)Wl4 + ((ks * NCT + ct) * 64 + lane) * 16);
      acc[ct] = __builtin_amdgcn_mfma_f32_16x16x32_bf16(a, b, acc[ct], 0, 0, 0);
    }
  }
  // D: col = lane&15, row = (lane>>4)*4 + j
#pragma unroll
  for (int j = 0; j < 4; j++) {
    int row = row0 + w * 16 + ((lane >> 4) << 2) + j;
    if (row < N_NODES) {
      float sc = dinv[row];
#pragma unroll
      for (int ct = 0; ct < NCT; ct++) {
        int col = ct * 16 + (lane & 15);
        Cb[(uint)row * FOUT + col] = (unsigned short)bfrn(acc[ct][j] * sc);
      }
    }
  }
}

// ---------------- prop, 128 bf16 feats, coefficient-free, 2 edges/wave ------------
// X is pre-scaled (x' = dinv * x); out = dinv[node] * (sum x'[c] + x'[node]).

template <bool RELU>
__global__ __launch_bounds__(256) void prop128s_k(const uint2* __restrict__ X,  // bf16x4
                                                  uint2* __restrict__ Yb,       // bf16x4
                                                  const int* __restrict__ off,
                                                  const uint* __restrict__ cc,
                                                  const float* __restrict__ dinv) {
  int node = blockIdx.x * 4 + (threadIdx.x >> 6);
  if (node >= N_NODES) return;
  uint lane = threadIdx.x & 63u;
  uint sub = lane >> 5, o32 = lane & 31u;
  float di = dinv[node];
  uint2 s = X[(uint)node * 32u + o32];
  float4 acc = make_float4(0.f, 0.f, 0.f, 0.f);
  int e = off[node], e1 = off[node + 1];
  for (; e + 7 < e1; e += 8) {  // 4 pairs = 8 edges
    uint c[4];
    uint2 v[4];
#pragma unroll
    for (int j = 0; j < 4; j++) c[j] = cc[e + 2 * j + sub];
#pragma unroll
    for (int j = 0; j < 4; j++) v[j] = X[c[j] * 32u + o32];
#pragma unroll
    for (int j = 0; j < 4; j++) {
      acc.x += bflo(v[j].x);
      acc.y += bfhi(v[j].x);
      acc.z += bflo(v[j].y);
      acc.w += bfhi(v[j].y);
    }
  }
  for (; e + 1 < e1; e += 2) {
    uint c = cc[e + sub];
    uint2 v = X[c * 32u + o32];
    acc.x += bflo(v.x);
    acc.y += bfhi(v.x);
    acc.z += bflo(v.y);
    acc.w += bfhi(v.y);
  }
  if (e < e1 && sub == 0) {  // odd tail edge: half-wave only
    uint c = cc[e];
    uint2 v = X[c * 32u + o32];
    acc.x += bflo(v.x);
    acc.y += bfhi(v.x);
    acc.z += bflo(v.y);
    acc.w += bfhi(v.y);
  }
  acc.x += __shfl_xor(acc.x, 32);
  acc.y += __shfl_xor(acc.y, 32);
  acc.z += __shfl_xor(acc.z, 32);
  acc.w += __shfl_xor(acc.w, 32);
  acc.x = (acc.x + bflo(s.x)) * di;
  acc.y = (acc.y + bfhi(s.x)) * di;
  acc.z = (acc.z + bflo(s.y)) * di;
  acc.w = (acc.w + bfhi(s.y)) * di;
  if (RELU) {
    acc.x = fmaxf(acc.x, 0.f); acc.y = fmaxf(acc.y, 0.f);
    acc.z = fmaxf(acc.z, 0.f); acc.w = fmaxf(acc.w, 0.f);
  }
  if (sub == 0) {
    uint2 p;
    p.x = bfpack(acc.x, acc.y);
    p.y = bfpack(acc.z, acc.w);
    Yb[(uint)node * 32u + o32] = p;
  }
}

// ---------------- prop, 64 bf16 feats, coefficient-free, fp32 out -----------------

__global__ __launch_bounds__(256) void prop64s_k(const uint* __restrict__ X,  // bf16x2
                                                 float2* __restrict__ Y,
                                                 const int* __restrict__ off,
                                                 const uint* __restrict__ cc,
                                                 const float* __restrict__ dinv) {
  int node = blockIdx.x * 4 + (threadIdx.x >> 6);
  if (node >= N_NODES) return;
  uint lane = threadIdx.x & 63u;
  uint sub = lane >> 5, o32 = lane & 31u;
  float di = dinv[node];
  uint s = X[(uint)node * 32u + o32];
  float2 acc = make_float2(0.f, 0.f);
  int e = off[node], e1 = off[node + 1];
  for (; e + 7 < e1; e += 8) {
    uint c[4];
    uint v[4];
#pragma unroll
    for (int j = 0; j < 4; j++) c[j] = cc[e + 2 * j + sub];
#pragma unroll
    for (int j = 0; j < 4; j++) v[j] = X[c[j] * 32u + o32];
#pragma unroll
    for (int j = 0; j < 4; j++) {
      acc.x += bflo(v[j]);
      acc.y += bfhi(v[j]);
    }
  }
  for (; e + 1 < e1; e += 2) {
    uint v = X[cc[e + sub] * 32u + o32];
    acc.x += bflo(v);
    acc.y += bfhi(v);
  }
  if (e < e1 && sub == 0) {
    uint v = X[cc[e] * 32u + o32];
    acc.x += bflo(v);
    acc.y += bfhi(v);
  }
  acc.x += __shfl_xor(acc.x, 32);
  acc.y += __shfl_xor(acc.y, 32);
  acc.x = (acc.x + bflo(s)) * di;
  acc.y = (acc.y + bfhi(s)) * di;
  if (sub == 0) Y[(uint)node * 32u + o32] = acc;
}

// ---------------- launch ----------------
// Pipeline (uses (PX)W == P(XW) and D^-1/2 factoring):
//   W01p = pack(bf16(W0@W1)); W2p = pack(bf16(W2)); gcur init
//   binbuf = bucket-sorted edges; off/dinv/cc from buckets
//   x0b = bf16(dinv ⊙ (feat @ W01))          [MFMA]
//   x1b = bf16(relu(dinv ⊙ gathersum(x0b)))  == relu(P(feat W0 W1))
//   t2b = bf16(dinv ⊙ (x1b @ W2))            [MFMA, aliases x0b]
//   out = dinv ⊙ gathersum(t2b)              == P(x1 W2)   (fp32)

extern "C" void kernel_launch(void* const* d_in, const int* in_sizes, int n_in,
                              void* d_out, int out_size, void* d_ws, size_t ws_size,
                              hipStream_t stream) {
  const float* feat = (const float*)d_in[0];
  const int* ei = (const int*)d_in[1];  // int32 per harness contract
  const float* W0 = (const float*)d_in[2];
  const float* W1 = (const float*)d_in[3];
  const float* W2 = (const float*)d_in[4];
  float2* out = (float2*)d_out;

  char* ws = (char*)d_ws;
  uint* x0b = (uint*)ws;       ws += (size_t)N_NODES * 128 * 2;  // bf16, 25.6 MB
  uint* x1b = (uint*)ws;       ws += (size_t)N_NODES * 128 * 2;  // bf16; binbuf aliases
  uint* cc = (uint*)ws;        ws += (size_t)N_EDGES * 4;        // col-only CSR
  float* dinv = (float*)ws;    ws += (size_t)N_NODES * 4;
  int* off = (int*)ws;         ws += (size_t)(N_NODES + 2) * 4;
  int* gcur = (int*)ws;        ws += (size_t)NB * 4;
  unsigned short* W01p = (unsigned short*)ws; ws += 128 * 128 * 2;
  unsigned short* W2p = (unsigned short*)ws;  ws += 128 * 64 * 2;
  unsigned* binbuf = (unsigned*)x1b;  // 391*CAP*4 = 8 MB, dead before x1b written
  unsigned short* t2b = (unsigned short*)x0b;  // bf16 N x 64, x0b dead after prop128s

  wpack_k<<<97, 256, 0, stream>>>(W0, W1, W2, W01p, W2p, gcur);
  binfused_k<<<NBLK, 256, 0, stream>>>(ei, gcur, binbuf);
  buckoff_k<<<NB, 256, 0, stream>>>(binbuf, gcur, off, dinv, cc);

  mgemm_k<128, false><<<(N_NODES + 63) / 64, 256, 0, stream>>>(feat, W01p, (unsigned short*)x0b, dinv);
  prop128s_k<true><<<(N_NODES + 3) / 4, 256, 0, stream>>>((const uint2*)x0b, (uint2*)x1b, off, cc, dinv);
  mgemm_k<64, true><<<(N_NODES + 63) / 64, 256, 0, stream>>>(x1b, W2p, t2b, dinv);
  prop64s_k<<<(N_NODES + 3) / 4, 256, 0, stream>>>((const uint*)t2b, out, off, cc, dinv);
}